// Round 3
// baseline (135254.016 us; speedup 1.0000x reference)
//
#include <hip/hip_runtime.h>
#include <hip/hip_bf16.h>

// TGCN: B=64, T=500, N=21, HID=128.
// Round 10 = Round 9 resubmitted (round-9 bench was an infra failure, no data).
// Round 9: round-8 column-split + explicit software-pipelined weight loads.
//   Round-8 regressed (20.2ms vs 12.5ms) because deduplicated weight streams
//   are all L1-misses (~200cyc L2 latency) and at VGPR=128 the compiler
//   serialized each c-iteration's loads behind the previous compute.
//   Fix: register ping-pong prefetch (issue group g+1's weight loads before
//   computing group g). Weights are tick-invariant -> loads can hoist freely.
//   Group sizes: P4 = 1 c-iter (2x20 float4), P1 = 2 c-iters, P2/P5 = 4 c-iters.
//   NEVER reorder per-element sums in the recurrence: every accumulator chain
//   keeps c-ascending order with identical intra-c sequence (bit-exact vs r7/r8).

#define NN 21
#define NROW 24            // padded rows (21,22,23 zero)
#define S 132              // padded float stride for H arrays (132%32==4)
#define SV4 33             // float4 stride
#define HID 128
#define TSTEPS 500
#define EDGES 210
#define NTHREADS 512       // 8 waves: 4 per group
#define RPT 3              // rows per row-group

// ws layout (float offsets) — unchanged
#define WS_A     0
#define WS_VEC   1600
#define WS_LZR1  3200
#define WS_LH1   36000
#define WS_WE2   52400
#define WS_LZR2  101600
#define WS_LH2   134400

typedef float v2f __attribute__((ext_vector_type(2)));

__device__ __forceinline__ v2f lo2(float4 w) { v2f v = {w.x, w.y}; return v; }
__device__ __forceinline__ v2f hi2(float4 w) { v2f v = {w.z, w.w}; return v; }
__device__ __forceinline__ void pkf(v2f& acc, float s, v2f w) {
    v2f ss = {s, s};
    acc = __builtin_elementwise_fma(ss, w, acc);
}
__device__ __forceinline__ float sigmoidf(float v) {
    return 1.0f / (1.0f + expf(-v));
}

// ---- Prologue: build normalized adjacency A (21x21) in fp64, store fp32 ----
__global__ void build_A(const int* __restrict__ ei, const float* __restrict__ ew,
                        float* __restrict__ Aout) {
    __shared__ double deg[NN];
    __shared__ double dinv[NN];
    __shared__ double Asm[NN * NN];
    int t = threadIdx.x;
    for (int k = t; k < NN * NN; k += blockDim.x) Asm[k] = 0.0;
    if (t < NN) deg[t] = 1.0;  // self loop weight 1
    __syncthreads();
    if (t == 0) {
        for (int e = 0; e < EDGES; e++) deg[ei[EDGES + e]] += (double)ew[e];
        for (int i = 0; i < NN; i++) dinv[i] = deg[i] > 0.0 ? 1.0 / sqrt(deg[i]) : 0.0;
        for (int e = 0; e < EDGES; e++) {
            int s = ei[e], d = ei[EDGES + e];
            Asm[d * NN + s] += dinv[s] * (double)ew[e] * dinv[d];
        }
        for (int i = 0; i < NN; i++) Asm[i * NN + i] += dinv[i] * dinv[i];
    }
    __syncthreads();
    for (int k = t; k < NROW * NN; k += blockDim.x)
        Aout[k] = (k < NN * NN) ? (float)Asm[k] : 0.0f;
}

// ---- Prologue: repack bottom halves of (256,128) concat weights ----------
__global__ void pack_bot(const float* __restrict__ w0, const float* __restrict__ w1,
                         float4* __restrict__ out, int ngate) {
    int t = blockIdx.x * blockDim.x + threadIdx.x;
    int per_c = ngate * 128;
    int total = 32 * per_c;
    if (t >= total) return;
    int c = t / per_c, rem = t - c * per_c;
    int gate = rem >> 7;
    int r2 = rem & 127;
    int k2 = r2 >> 6;
    int f0 = r2 & 63;
    int k = 4 * c + 2 * k2;
    const float* src = (gate == 0) ? w0 : w1;
    float4 v;
    v.x = src[(128 + k) * 128 + f0];
    v.y = src[(128 + k) * 128 + f0 + 64];
    v.z = src[(128 + k + 1) * 128 + f0];
    v.w = src[(128 + k + 1) * 128 + f0 + 64];
    out[t] = v;
}

// ---- Prologue: Weff2_g = Wg_2 @ lgw_2_top, pair-interleaved, fp64 accum ----
__global__ void make_weff2(const float* __restrict__ Wz2, const float* __restrict__ Wr2,
                           const float* __restrict__ Wh2,
                           const float* __restrict__ lzw2, const float* __restrict__ lrw2,
                           const float* __restrict__ lhw2,
                           float4* __restrict__ out) {
    int t = blockIdx.x * blockDim.x + threadIdx.x;
    if (t >= 32 * 384) return;
    int c = t / 384, rem = t - c * 384;
    int g = rem >> 7;
    int r2 = rem & 127;
    int k2 = r2 >> 6;
    int f0 = r2 & 63;
    int k = 4 * c + 2 * k2;
    const float* W = (g == 0) ? Wz2 : (g == 1) ? Wr2 : Wh2;
    const float* L = (g == 0) ? lzw2 : (g == 1) ? lrw2 : lhw2;
    double a0 = 0, a1 = 0, a2 = 0, a3 = 0;
    for (int m = 0; m < 128; m++) {
        double w0 = (double)W[k * 128 + m];
        double w1 = (double)W[(k + 1) * 128 + m];
        a0 += w0 * (double)L[m * 128 + f0];
        a1 += w0 * (double)L[m * 128 + f0 + 64];
        a2 += w1 * (double)L[m * 128 + f0];
        a3 += w1 * (double)L[m * 128 + f0 + 64];
    }
    out[t] = make_float4((float)a0, (float)a1, (float)a2, (float)a3);
}

// ---- Prologue: layer-1 effective row vectors + all bias consts (fp64) ----
__global__ void make_vecs(const float* __restrict__ Wz1, const float* __restrict__ Wr1,
                          const float* __restrict__ Wh1,
                          const float* __restrict__ bz1, const float* __restrict__ br1,
                          const float* __restrict__ bh1,
                          const float* __restrict__ lzw1, const float* __restrict__ lrw1,
                          const float* __restrict__ lhw1,
                          const float* __restrict__ lzb1, const float* __restrict__ lrb1,
                          const float* __restrict__ lhb1,
                          const float* __restrict__ bz2, const float* __restrict__ br2,
                          const float* __restrict__ bh2,
                          const float* __restrict__ lzw2, const float* __restrict__ lrw2,
                          const float* __restrict__ lhw2,
                          const float* __restrict__ lzb2, const float* __restrict__ lrb2,
                          const float* __restrict__ lhb2,
                          float* __restrict__ out) {
    int t = blockIdx.x * blockDim.x + threadIdx.x;
    if (t >= 9 * 128) return;
    int v = t >> 7, f = t & 127;
    double acc = 0.0;
    if (v < 3) {
        const float* W = (v == 0) ? Wz1 : (v == 1) ? Wr1 : Wh1;
        const float* L = (v == 0) ? lzw1 : (v == 1) ? lrw1 : lhw1;
        for (int m = 0; m < 128; m++) acc += (double)W[m] * (double)L[m * 128 + f];
    } else if (v < 6) {
        int g = v - 3;
        const float* bb = (g == 0) ? bz1 : (g == 1) ? br1 : bh1;
        const float* L  = (g == 0) ? lzw1 : (g == 1) ? lrw1 : lhw1;
        const float* lb = (g == 0) ? lzb1 : (g == 1) ? lrb1 : lhb1;
        for (int m = 0; m < 128; m++) acc += (double)bb[m] * (double)L[m * 128 + f];
        acc += (double)lb[f];
    } else {
        int g = v - 6;
        const float* bb = (g == 0) ? bz2 : (g == 1) ? br2 : bh2;
        const float* L  = (g == 0) ? lzw2 : (g == 1) ? lrw2 : lhw2;
        const float* lb = (g == 0) ? lzb2 : (g == 1) ? lrb2 : lhb2;
        for (int m = 0; m < 128; m++) acc += (double)bb[m] * (double)L[m * 128 + f];
        acc += (double)lb[f];
    }
    out[t] = (float)acc;
}

// ---- Main: one block per batch, layer-pipelined groups, 2 barriers/tick ----
__global__ __launch_bounds__(NTHREADS, 2) void tgcn_main(
    const float* __restrict__ x,       // (64,500,21)
    const float* __restrict__ ws,
    const float* __restrict__ cls_w,   // (128,1)
    const float* __restrict__ cls_b,   // (1,)
    float* __restrict__ out)           // (64,)
{
    const int b  = blockIdx.x;
    const int t  = threadIdx.x;
    const bool isA = (t < 256);                              // wave-uniform
    const int lt = t & 255;
    const int gw = __builtin_amdgcn_readfirstlane(lt >> 6);  // wave in group 0..3
    const int lane = t & 63;
    const int p  = lane & 7;          // pair slot
    const int rg = lane >> 3;         // row group 0..7
    const int rb = rg * RPT;          // first row of this lane
    const int f0A = gw * 16 + p;      // first pair:  cols (f0A, f0A+64)
    const int f0B = f0A + 8;          // second pair: cols (f0B, f0B+64)

    __shared__ __align__(16) float sH1[2][NROW * S];  // double-buffered
    __shared__ __align__(16) float sH2[NROW * S];
    __shared__ __align__(16) float sHR1[NROW * S];
    __shared__ __align__(16) float sHR2[NROW * S];
    __shared__ __align__(16) float sAH[NROW * S];
    __shared__ float sA[NROW * NN];
    __shared__ float sax[2][NROW];
    __shared__ double sredD[HID];
    __shared__ double sredE[HID];

    const float*  vecs = ws + WS_VEC;
    const float4* Lzr1 = (const float4*)(ws + WS_LZR1);
    const float4* Lh1  = (const float4*)(ws + WS_LH1);
    const float4* We2  = (const float4*)(ws + WS_WE2);
    const float4* Lzr2 = (const float4*)(ws + WS_LZR2);
    const float4* Lh2  = (const float4*)(ws + WS_LH2);

    const float4* HR1v = (const float4*)sHR1;
    const float4* HR2v = (const float4*)sHR2;
    const float4* AHv  = (const float4*)sAH;
    const float4* H2v  = (const float4*)sH2;

    for (int k = t; k < 2 * NROW * S; k += NTHREADS) ((float*)sH1)[k] = 0.0f;
    for (int k = t; k < NROW * S; k += NTHREADS) {
        sH2[k] = 0.0f; sHR1[k] = 0.0f; sHR2[k] = 0.0f; sAH[k] = 0.0f;
    }
    for (int k = t; k < NROW * NN; k += NTHREADS) sA[k] = ws[WS_A + k];

    // per-pair constants (two pairs per lane)
    const v2f wz1vA = {vecs[f0A],        vecs[f0A + 64]};
    const v2f wz1vB = {vecs[f0B],        vecs[f0B + 64]};
    const v2f wr1vA = {vecs[128 + f0A],  vecs[128 + f0A + 64]};
    const v2f wr1vB = {vecs[128 + f0B],  vecs[128 + f0B + 64]};
    const v2f wh1vA = {vecs[256 + f0A],  vecs[256 + f0A + 64]};
    const v2f wh1vB = {vecs[256 + f0B],  vecs[256 + f0B + 64]};
    const v2f cz1vA = {vecs[384 + f0A],  vecs[384 + f0A + 64]};
    const v2f cz1vB = {vecs[384 + f0B],  vecs[384 + f0B + 64]};
    const v2f cr1vA = {vecs[512 + f0A],  vecs[512 + f0A + 64]};
    const v2f cr1vB = {vecs[512 + f0B],  vecs[512 + f0B + 64]};
    const v2f ch1vA = {vecs[640 + f0A],  vecs[640 + f0A + 64]};
    const v2f ch1vB = {vecs[640 + f0B],  vecs[640 + f0B + 64]};
    const v2f cz2vA = {vecs[768 + f0A],  vecs[768 + f0A + 64]};
    const v2f cz2vB = {vecs[768 + f0B],  vecs[768 + f0B + 64]};
    const v2f cr2vA = {vecs[896 + f0A],  vecs[896 + f0A + 64]};
    const v2f cr2vB = {vecs[896 + f0B],  vecs[896 + f0B + 64]};
    const v2f ch2vA = {vecs[1024 + f0A], vecs[1024 + f0A + 64]};
    const v2f ch2vB = {vecs[1024 + f0B], vecs[1024 + f0B + 64]};

    __syncthreads();

    const float* xb = x + (size_t)b * (TSTEPS * NN);
    if (t < NROW) {  // sax for steps 0 and 1 (slot = s&1)
        float a0s = 0.0f, a1s = 0.0f;
        for (int j = 0; j < NN; j++) {
            a0s = fmaf(sA[t * NN + j], xb[j], a0s);
            a1s = fmaf(sA[t * NN + j], xb[NN + j], a1s);
        }
        sax[0][t] = a0s;
        sax[1][t] = a1s;
    }
    __syncthreads();

    // ---- persistent per-thread state carried across barriers ----
    float axp[RPT];                         // A: P1 -> P2
    v2f zg[RPT][2], h1c[RPT][2];            // A: P1 -> P2
    v2f ph[RPT][2], z2[RPT][2], h2c[RPT][2];// B: P4 -> P5 (crosses b2)
    double oA0 = 0.0, oA1 = 0.0, oB0 = 0.0, oB1 = 0.0;  // B output accum

    // ================= phase lambdas (pipelined weight loads) =================
    // P1 (A): layer-1 z,r gates for step s; reads H1 state s-1 = buf[(s+1)&1]
    // Weight pipeline: 2-c groups, ping-pong (2 x 16 float4).
    auto l1_p1 = [&](int s) {
        const float* H1rd = sH1[(s + 1) & 1];
        const float4* H1c = (const float4*)H1rd;
        #pragma unroll
        for (int r = 0; r < RPT; r++) axp[r] = sax[s & 1][rb + r];
        v2f az[RPT][2], ar[RPT][2];
        #pragma unroll
        for (int r = 0; r < RPT; r++) {
            az[r][0] = __builtin_elementwise_fma((v2f){axp[r], axp[r]}, wz1vA, cz1vA);
            az[r][1] = __builtin_elementwise_fma((v2f){axp[r], axp[r]}, wz1vB, cz1vB);
            ar[r][0] = __builtin_elementwise_fma((v2f){axp[r], axp[r]}, wr1vA, cr1vA);
            ar[r][1] = __builtin_elementwise_fma((v2f){axp[r], axp[r]}, wr1vB, cr1vB);
        }
        float4 w0[16], w1[16];
        auto ld = [&](float4* w, int c0) {
            #pragma unroll
            for (int cc = 0; cc < 2; cc++) {
                const int c = c0 + cc;
                w[cc * 8 + 0] = Lzr1[c * 256 + f0A];
                w[cc * 8 + 1] = Lzr1[c * 256 + 64 + f0A];
                w[cc * 8 + 2] = Lzr1[c * 256 + 128 + f0A];
                w[cc * 8 + 3] = Lzr1[c * 256 + 192 + f0A];
                w[cc * 8 + 4] = Lzr1[c * 256 + f0B];
                w[cc * 8 + 5] = Lzr1[c * 256 + 64 + f0B];
                w[cc * 8 + 6] = Lzr1[c * 256 + 128 + f0B];
                w[cc * 8 + 7] = Lzr1[c * 256 + 192 + f0B];
            }
        };
        auto cp = [&](const float4* w, int c0) {
            #pragma unroll
            for (int cc = 0; cc < 2; cc++) {
                const int c = c0 + cc;
                const float4 wz0A = w[cc * 8 + 0], wz1A = w[cc * 8 + 1];
                const float4 wr0A = w[cc * 8 + 2], wr1A = w[cc * 8 + 3];
                const float4 wz0B = w[cc * 8 + 4], wz1B = w[cc * 8 + 5];
                const float4 wr0B = w[cc * 8 + 6], wr1B = w[cc * 8 + 7];
                #pragma unroll
                for (int r = 0; r < RPT; r++) {
                    const float4 h = H1c[(rb + r) * SV4 + c];
                    pkf(az[r][0], h.x, lo2(wz0A)); pkf(az[r][0], h.y, hi2(wz0A));
                    pkf(az[r][0], h.z, lo2(wz1A)); pkf(az[r][0], h.w, hi2(wz1A));
                    pkf(ar[r][0], h.x, lo2(wr0A)); pkf(ar[r][0], h.y, hi2(wr0A));
                    pkf(ar[r][0], h.z, lo2(wr1A)); pkf(ar[r][0], h.w, hi2(wr1A));
                    pkf(az[r][1], h.x, lo2(wz0B)); pkf(az[r][1], h.y, hi2(wz0B));
                    pkf(az[r][1], h.z, lo2(wz1B)); pkf(az[r][1], h.w, hi2(wz1B));
                    pkf(ar[r][1], h.x, lo2(wr0B)); pkf(ar[r][1], h.y, hi2(wr0B));
                    pkf(ar[r][1], h.z, lo2(wr1B)); pkf(ar[r][1], h.w, hi2(wr1B));
                }
            }
        };
        ld(w0, 0);
        for (int cb = 0; cb < 32; cb += 4) {
            ld(w1, cb + 2);
            cp(w0, cb);
            if (cb + 4 < 32) ld(w0, cb + 4);
            cp(w1, cb + 2);
        }
        #pragma unroll
        for (int r = 0; r < RPT; r++) {
            const int row = rb + r;
            zg[r][0].x = sigmoidf(az[r][0].x);
            zg[r][0].y = sigmoidf(az[r][0].y);
            zg[r][1].x = sigmoidf(az[r][1].x);
            zg[r][1].y = sigmoidf(az[r][1].y);
            const float rA0 = sigmoidf(ar[r][0].x);
            const float rA1 = sigmoidf(ar[r][0].y);
            const float rB0 = sigmoidf(ar[r][1].x);
            const float rB1 = sigmoidf(ar[r][1].y);
            h1c[r][0].x = H1rd[row * S + f0A];
            h1c[r][0].y = H1rd[row * S + f0A + 64];
            h1c[r][1].x = H1rd[row * S + f0B];
            h1c[r][1].y = H1rd[row * S + f0B + 64];
            sHR1[row * S + f0A]      = h1c[r][0].x * rA0;
            sHR1[row * S + f0A + 64] = h1c[r][0].y * rA1;
            sHR1[row * S + f0B]      = h1c[r][1].x * rB0;
            sHR1[row * S + f0B + 64] = h1c[r][1].y * rB1;
        }
    };

    // P2 (A): layer-1 h gate + H1 update. Weight pipeline: 4-c groups.
    auto l1_p2 = [&](int s) {
        float* H1wr = sH1[s & 1];
        v2f ah[RPT][2];
        #pragma unroll
        for (int r = 0; r < RPT; r++) {
            ah[r][0] = __builtin_elementwise_fma((v2f){axp[r], axp[r]}, wh1vA, ch1vA);
            ah[r][1] = __builtin_elementwise_fma((v2f){axp[r], axp[r]}, wh1vB, ch1vB);
        }
        float4 w0[16], w1[16];
        auto ld = [&](float4* w, int c0) {
            #pragma unroll
            for (int cc = 0; cc < 4; cc++) {
                const int c = c0 + cc;
                w[cc * 4 + 0] = Lh1[c * 128 + f0A];
                w[cc * 4 + 1] = Lh1[c * 128 + 64 + f0A];
                w[cc * 4 + 2] = Lh1[c * 128 + f0B];
                w[cc * 4 + 3] = Lh1[c * 128 + 64 + f0B];
            }
        };
        auto cp = [&](const float4* w, int c0) {
            #pragma unroll
            for (int cc = 0; cc < 4; cc++) {
                const int c = c0 + cc;
                const float4 wh0A = w[cc * 4 + 0], wh1A = w[cc * 4 + 1];
                const float4 wh0B = w[cc * 4 + 2], wh1B = w[cc * 4 + 3];
                #pragma unroll
                for (int r = 0; r < RPT; r++) {
                    const float4 q = HR1v[(rb + r) * SV4 + c];
                    pkf(ah[r][0], q.x, lo2(wh0A)); pkf(ah[r][0], q.y, hi2(wh0A));
                    pkf(ah[r][0], q.z, lo2(wh1A)); pkf(ah[r][0], q.w, hi2(wh1A));
                    pkf(ah[r][1], q.x, lo2(wh0B)); pkf(ah[r][1], q.y, hi2(wh0B));
                    pkf(ah[r][1], q.z, lo2(wh1B)); pkf(ah[r][1], q.w, hi2(wh1B));
                }
            }
        };
        ld(w0, 0);
        for (int cb = 0; cb < 32; cb += 8) {
            ld(w1, cb + 4);
            cp(w0, cb);
            if (cb + 8 < 32) ld(w0, cb + 8);
            cp(w1, cb + 4);
        }
        #pragma unroll
        for (int r = 0; r < RPT; r++) {
            const int row = rb + r;
            const float n0 = fmaf(zg[r][0].x, h1c[r][0].x, (1.0f - zg[r][0].x) * tanhf(ah[r][0].x));
            const float n1 = fmaf(zg[r][0].y, h1c[r][0].y, (1.0f - zg[r][0].y) * tanhf(ah[r][0].y));
            const float n2 = fmaf(zg[r][1].x, h1c[r][1].x, (1.0f - zg[r][1].x) * tanhf(ah[r][1].x));
            const float n3 = fmaf(zg[r][1].y, h1c[r][1].y, (1.0f - zg[r][1].y) * tanhf(ah[r][1].y));
            H1wr[row * S + f0A]      = n0;
            H1wr[row * S + f0A + 64] = n1;
            H1wr[row * S + f0B]      = n2;
            H1wr[row * S + f0B + 64] = n3;
        }
    };

    // P3 (B): AH = A @ H1(state tt) for own rows/cols (LDS only)
    auto l2_p3 = [&](int tt) {
        const float* H1rd = sH1[tt & 1];
        v2f aa[RPT][2];
        #pragma unroll
        for (int r = 0; r < RPT; r++) { aa[r][0] = (v2f){0.0f, 0.0f}; aa[r][1] = (v2f){0.0f, 0.0f}; }
        #pragma unroll 3
        for (int j = 0; j < NN; j++) {
            const v2f hjA = {H1rd[j * S + f0A], H1rd[j * S + f0A + 64]};
            const v2f hjB = {H1rd[j * S + f0B], H1rd[j * S + f0B + 64]};
            #pragma unroll
            for (int r = 0; r < RPT; r++) {
                const float arj = sA[(rb + r) * NN + j];
                aa[r][0] = __builtin_elementwise_fma((v2f){arj, arj}, hjA, aa[r][0]);
                aa[r][1] = __builtin_elementwise_fma((v2f){arj, arj}, hjB, aa[r][1]);
            }
        }
        #pragma unroll
        for (int r = 0; r < RPT; r++) {
            const int row = rb + r;
            sAH[row * S + f0A]      = aa[r][0].x;
            sAH[row * S + f0A + 64] = aa[r][0].y;
            sAH[row * S + f0B]      = aa[r][1].x;
            sAH[row * S + f0B + 64] = aa[r][1].y;
        }
    };

    // P4 (B): layer-2 gcn + z,r gates; h-gate a-chunk partials into ph.
    // Weight pipeline: 1-c groups, ping-pong (2 x 20 float4).
    auto l2_p4 = [&]() {
        v2f pz[RPT][2], pr[RPT][2];
        #pragma unroll
        for (int r = 0; r < RPT; r++) {
            pz[r][0] = cz2vA; pz[r][1] = cz2vB;
            pr[r][0] = cr2vA; pr[r][1] = cr2vB;
            ph[r][0] = ch2vA; ph[r][1] = ch2vB;
        }
        float4 w0[20], w1[20];
        auto ld = [&](float4* w, int c) {
            w[0]  = We2[c * 384 + f0A];
            w[1]  = We2[c * 384 + 64 + f0A];
            w[2]  = We2[c * 384 + 128 + f0A];
            w[3]  = We2[c * 384 + 192 + f0A];
            w[4]  = We2[c * 384 + 256 + f0A];
            w[5]  = We2[c * 384 + 320 + f0A];
            w[6]  = Lzr2[c * 256 + f0A];
            w[7]  = Lzr2[c * 256 + 64 + f0A];
            w[8]  = Lzr2[c * 256 + 128 + f0A];
            w[9]  = Lzr2[c * 256 + 192 + f0A];
            w[10] = We2[c * 384 + f0B];
            w[11] = We2[c * 384 + 64 + f0B];
            w[12] = We2[c * 384 + 128 + f0B];
            w[13] = We2[c * 384 + 192 + f0B];
            w[14] = We2[c * 384 + 256 + f0B];
            w[15] = We2[c * 384 + 320 + f0B];
            w[16] = Lzr2[c * 256 + f0B];
            w[17] = Lzr2[c * 256 + 64 + f0B];
            w[18] = Lzr2[c * 256 + 128 + f0B];
            w[19] = Lzr2[c * 256 + 192 + f0B];
        };
        auto cp = [&](const float4* w, int c) {
            float4 av[RPT], qv[RPT];
            #pragma unroll
            for (int r = 0; r < RPT; r++) {
                av[r] = AHv[(rb + r) * SV4 + c];
                qv[r] = H2v[(rb + r) * SV4 + c];
            }
            {   // pair A half (a-chunk then q-chunk per gate — round-8 order)
                const float4 wz0 = w[0], wz1 = w[1], wr0 = w[2], wr1 = w[3];
                const float4 wh0 = w[4], wh1 = w[5];
                const float4 lz0 = w[6], lz1 = w[7], lr0 = w[8], lr1 = w[9];
                #pragma unroll
                for (int r = 0; r < RPT; r++) {
                    const float4 a = av[r], q = qv[r];
                    pkf(pz[r][0], a.x, lo2(wz0)); pkf(pz[r][0], a.y, hi2(wz0));
                    pkf(pz[r][0], a.z, lo2(wz1)); pkf(pz[r][0], a.w, hi2(wz1));
                    pkf(pz[r][0], q.x, lo2(lz0)); pkf(pz[r][0], q.y, hi2(lz0));
                    pkf(pz[r][0], q.z, lo2(lz1)); pkf(pz[r][0], q.w, hi2(lz1));
                    pkf(pr[r][0], a.x, lo2(wr0)); pkf(pr[r][0], a.y, hi2(wr0));
                    pkf(pr[r][0], a.z, lo2(wr1)); pkf(pr[r][0], a.w, hi2(wr1));
                    pkf(pr[r][0], q.x, lo2(lr0)); pkf(pr[r][0], q.y, hi2(lr0));
                    pkf(pr[r][0], q.z, lo2(lr1)); pkf(pr[r][0], q.w, hi2(lr1));
                    pkf(ph[r][0], a.x, lo2(wh0)); pkf(ph[r][0], a.y, hi2(wh0));
                    pkf(ph[r][0], a.z, lo2(wh1)); pkf(ph[r][0], a.w, hi2(wh1));
                }
            }
            {   // pair B half
                const float4 wz0 = w[10], wz1 = w[11], wr0 = w[12], wr1 = w[13];
                const float4 wh0 = w[14], wh1 = w[15];
                const float4 lz0 = w[16], lz1 = w[17], lr0 = w[18], lr1 = w[19];
                #pragma unroll
                for (int r = 0; r < RPT; r++) {
                    const float4 a = av[r], q = qv[r];
                    pkf(pz[r][1], a.x, lo2(wz0)); pkf(pz[r][1], a.y, hi2(wz0));
                    pkf(pz[r][1], a.z, lo2(wz1)); pkf(pz[r][1], a.w, hi2(wz1));
                    pkf(pz[r][1], q.x, lo2(lz0)); pkf(pz[r][1], q.y, hi2(lz0));
                    pkf(pz[r][1], q.z, lo2(lz1)); pkf(pz[r][1], q.w, hi2(lz1));
                    pkf(pr[r][1], a.x, lo2(wr0)); pkf(pr[r][1], a.y, hi2(wr0));
                    pkf(pr[r][1], a.z, lo2(wr1)); pkf(pr[r][1], a.w, hi2(wr1));
                    pkf(pr[r][1], q.x, lo2(lr0)); pkf(pr[r][1], q.y, hi2(lr0));
                    pkf(pr[r][1], q.z, lo2(lr1)); pkf(pr[r][1], q.w, hi2(lr1));
                    pkf(ph[r][1], a.x, lo2(wh0)); pkf(ph[r][1], a.y, hi2(wh0));
                    pkf(ph[r][1], a.z, lo2(wh1)); pkf(ph[r][1], a.w, hi2(wh1));
                }
            }
        };
        ld(w0, 0);
        for (int c = 0; c < 32; c += 2) {
            ld(w1, c + 1);
            cp(w0, c);
            if (c + 2 < 32) ld(w0, c + 2);
            cp(w1, c + 1);
        }
        #pragma unroll
        for (int r = 0; r < RPT; r++) {
            const int row = rb + r;
            z2[r][0].x = sigmoidf(pz[r][0].x);
            z2[r][0].y = sigmoidf(pz[r][0].y);
            z2[r][1].x = sigmoidf(pz[r][1].x);
            z2[r][1].y = sigmoidf(pz[r][1].y);
            const float rA0 = sigmoidf(pr[r][0].x);
            const float rA1 = sigmoidf(pr[r][0].y);
            const float rB0 = sigmoidf(pr[r][1].x);
            const float rB1 = sigmoidf(pr[r][1].y);
            h2c[r][0].x = sH2[row * S + f0A];
            h2c[r][0].y = sH2[row * S + f0A + 64];
            h2c[r][1].x = sH2[row * S + f0B];
            h2c[r][1].y = sH2[row * S + f0B + 64];
            sHR2[row * S + f0A]      = h2c[r][0].x * rA0;
            sHR2[row * S + f0A + 64] = h2c[r][0].y * rA1;
            sHR2[row * S + f0B]      = h2c[r][1].x * rB0;
            sHR2[row * S + f0B + 64] = h2c[r][1].y * rB1;
        }
    };

    // P5 (B): layer-2 h gate finish + H2 update + output accum.
    // Weight pipeline: 4-c groups.
    auto l2_p5 = [&]() {
        float4 w0[16], w1[16];
        auto ld = [&](float4* w, int c0) {
            #pragma unroll
            for (int cc = 0; cc < 4; cc++) {
                const int c = c0 + cc;
                w[cc * 4 + 0] = Lh2[c * 128 + f0A];
                w[cc * 4 + 1] = Lh2[c * 128 + 64 + f0A];
                w[cc * 4 + 2] = Lh2[c * 128 + f0B];
                w[cc * 4 + 3] = Lh2[c * 128 + 64 + f0B];
            }
        };
        auto cp = [&](const float4* w, int c0) {
            #pragma unroll
            for (int cc = 0; cc < 4; cc++) {
                const int c = c0 + cc;
                const float4 lh0A = w[cc * 4 + 0], lh1A = w[cc * 4 + 1];
                const float4 lh0B = w[cc * 4 + 2], lh1B = w[cc * 4 + 3];
                #pragma unroll
                for (int r = 0; r < RPT; r++) {
                    const float4 q = HR2v[(rb + r) * SV4 + c];
                    pkf(ph[r][0], q.x, lo2(lh0A)); pkf(ph[r][0], q.y, hi2(lh0A));
                    pkf(ph[r][0], q.z, lo2(lh1A)); pkf(ph[r][0], q.w, hi2(lh1A));
                    pkf(ph[r][1], q.x, lo2(lh0B)); pkf(ph[r][1], q.y, hi2(lh0B));
                    pkf(ph[r][1], q.z, lo2(lh1B)); pkf(ph[r][1], q.w, hi2(lh1B));
                }
            }
        };
        ld(w0, 0);
        for (int cb = 0; cb < 32; cb += 8) {
            ld(w1, cb + 4);
            cp(w0, cb);
            if (cb + 8 < 32) ld(w0, cb + 8);
            cp(w1, cb + 4);
        }
        #pragma unroll
        for (int r = 0; r < RPT; r++) {
            const int row = rb + r;
            const float mA0 = fmaf(z2[r][0].x, h2c[r][0].x, (1.0f - z2[r][0].x) * tanhf(ph[r][0].x));
            const float mA1 = fmaf(z2[r][0].y, h2c[r][0].y, (1.0f - z2[r][0].y) * tanhf(ph[r][0].y));
            const float mB0 = fmaf(z2[r][1].x, h2c[r][1].x, (1.0f - z2[r][1].x) * tanhf(ph[r][1].x));
            const float mB1 = fmaf(z2[r][1].y, h2c[r][1].y, (1.0f - z2[r][1].y) * tanhf(ph[r][1].y));
            sH2[row * S + f0A]      = mA0;
            sH2[row * S + f0A + 64] = mA1;
            sH2[row * S + f0B]      = mB0;
            sH2[row * S + f0B + 64] = mB1;
            if (row < NN) {
                oA0 += (double)mA0; oA1 += (double)mA1;
                oB0 += (double)mB0; oB1 += (double)mB1;
            }
        }
    };

    // ======== pipeline prologue: A computes step 0 ========
    if (isA) l1_p1(0);
    __syncthreads();
    if (isA) l1_p2(0);
    __syncthreads();

    // ======== main ticks: 2 barriers each ========
    for (int k = 0; k < TSTEPS; k++) {
        // alpha
        if (isA) {
            if (k + 1 < TSTEPS) l1_p1(k + 1);
        } else {
            if (k >= 1) l2_p5();     // finish step k-1
            l2_p3(k);
        }
        __syncthreads();  // b1: publishes sHR1(k+1), sAH(k), sH2(k-1)
        // beta
        if (isA) {
            if (k + 1 < TSTEPS) l1_p2(k + 1);
            if (t < NROW && k + 2 < TSTEPS) {   // sax prefetch for step k+2
                const float* xt = xb + (size_t)(k + 2) * NN;
                float a = 0.0f;
                for (int j = 0; j < NN; j++) a = fmaf(sA[t * NN + j], xt[j], a);
                sax[(k + 2) & 1][t] = a;
            }
        } else {
            l2_p4();
        }
        __syncthreads();  // b2: publishes H1(k+1), sHR2(k), sax(k+2)
    }

    // ---------- Epilogue: finish step T-1, mean over (T, nodes), cls ----------
    if (!isA) {
        l2_p5();  // step T-1 (sHR2 published at final b2)
        double vA0 = oA0, vA1 = oA1, vB0 = oB0, vB1 = oB1;
        #pragma unroll
        for (int off = 32; off >= 8; off >>= 1) {
            vA0 += __shfl_down(vA0, off, 64);
            vA1 += __shfl_down(vA1, off, 64);
            vB0 += __shfl_down(vB0, off, 64);
            vB1 += __shfl_down(vB1, off, 64);
        }
        if (rg == 0) {   // lane p of each B wave owns 4 columns
            sredD[f0A]      = vA0;
            sredD[f0A + 64] = vA1;
            sredD[f0B]      = vB0;
            sredD[f0B + 64] = vB1;
        }
    }
    __syncthreads();
    if (t < HID) {
        sredE[t] = (sredD[t] / (double)(TSTEPS * NN)) * (double)cls_w[t];
    }
    __syncthreads();
    if (t < 64) {
        double v = sredE[t] + sredE[t + 64];
        for (int off = 32; off; off >>= 1) v += __shfl_down(v, off, 64);
        if (t == 0) out[b] = (float)(v + (double)cls_b[0]);
    }
}

extern "C" void kernel_launch(void* const* d_in, const int* in_sizes, int n_in,
                              void* d_out, int out_size, void* d_ws, size_t ws_size,
                              hipStream_t stream) {
    const float* x    = (const float*)d_in[0];
    const int*   ei   = (const int*)  d_in[1];
    const float* ew   = (const float*)d_in[2];
    const float* Wz1  = (const float*)d_in[3];
    const float* bz1  = (const float*)d_in[4];
    const float* lzw1 = (const float*)d_in[5];
    const float* lzb1 = (const float*)d_in[6];
    const float* Wr1  = (const float*)d_in[7];
    const float* br1  = (const float*)d_in[8];
    const float* lrw1 = (const float*)d_in[9];
    const float* lrb1 = (const float*)d_in[10];
    const float* Wh1  = (const float*)d_in[11];
    const float* bh1  = (const float*)d_in[12];
    const float* lhw1 = (const float*)d_in[13];
    const float* lhb1 = (const float*)d_in[14];
    const float* Wz2  = (const float*)d_in[15];
    const float* bz2  = (const float*)d_in[16];
    const float* lzw2 = (const float*)d_in[17];
    const float* lzb2 = (const float*)d_in[18];
    const float* Wr2  = (const float*)d_in[19];
    const float* br2  = (const float*)d_in[20];
    const float* lrw2 = (const float*)d_in[21];
    const float* lrb2 = (const float*)d_in[22];
    const float* Wh2  = (const float*)d_in[23];
    const float* bh2  = (const float*)d_in[24];
    const float* lhw2 = (const float*)d_in[25];
    const float* lhb2 = (const float*)d_in[26];
    const float* clsw = (const float*)d_in[27];
    const float* clsb = (const float*)d_in[28];

    float* ws   = (float*)d_ws;
    float* outp = (float*)d_out;

    build_A<<<1, 64, 0, stream>>>(ei, ew, ws + WS_A);
    pack_bot<<<32, 256, 0, stream>>>(lzw1, lrw1, (float4*)(ws + WS_LZR1), 2);
    pack_bot<<<16, 256, 0, stream>>>(lhw1, lhw1, (float4*)(ws + WS_LH1), 1);
    pack_bot<<<32, 256, 0, stream>>>(lzw2, lrw2, (float4*)(ws + WS_LZR2), 2);
    pack_bot<<<16, 256, 0, stream>>>(lhw2, lhw2, (float4*)(ws + WS_LH2), 1);
    make_weff2<<<48, 256, 0, stream>>>(Wz2, Wr2, Wh2, lzw2, lrw2, lhw2,
                                       (float4*)(ws + WS_WE2));
    make_vecs<<<5, 256, 0, stream>>>(Wz1, Wr1, Wh1, bz1, br1, bh1,
                                     lzw1, lrw1, lhw1, lzb1, lrb1, lhb1,
                                     bz2, br2, bh2, lzw2, lrw2, lhw2,
                                     lzb2, lrb2, lhb2, ws + WS_VEC);
    tgcn_main<<<64, NTHREADS, 0, stream>>>(x, ws, clsw, clsb, outp);
}

// Round 4
// 42105.109 us; speedup vs baseline: 3.2123x; 3.2123x over previous
//
#include <hip/hip_runtime.h>
#include <hip/hip_bf16.h>

// TGCN: B=64, T=500, N=21, HID=128.
// Round 11: fix the round-9/10 spill.
//   rocprof: VGPR_Count=128 (launch_bounds(512,2) -> CUDA-style 2 blocks/CU
//   -> 4 waves/SIMD -> 128-VGPR cap) while ping-pong needed ~250 -> scratch
//   spill -> FETCH 5.8GB + WRITE 8.7GB per dispatch, VALUBusy 2.5%, 135ms.
//   Fixes:
//   (1) __launch_bounds__(512, 1): 2 waves/SIMD, 256-VGPR cap. Grid is 64
//       blocks on 256 CUs -> 1 block/CU regardless; no occupancy loss.
//   (2) Consts (18 v2f = 36 VGPR/thread) moved to LDS sVec, re-read per use.
//   (3) P4 split into per-pair passes with 1-c ping-pong groups (2x10 float4
//       = 80 VGPR weight buffers instead of 160). Chains stay c-ascending
//       with identical intra-c order -> bit-exact (absmax 0.0).
//   NEVER reorder per-element sums in the recurrence.

#define NN 21
#define NROW 24            // padded rows (21,22,23 zero)
#define S 132              // padded float stride for H arrays (132%32==4)
#define SV4 33             // float4 stride
#define HID 128
#define TSTEPS 500
#define EDGES 210
#define NTHREADS 512       // 8 waves: 4 per group
#define RPT 3              // rows per row-group

// ws layout (float offsets) — unchanged
#define WS_A     0
#define WS_VEC   1600
#define WS_LZR1  3200
#define WS_LH1   36000
#define WS_WE2   52400
#define WS_LZR2  101600
#define WS_LH2   134400

typedef float v2f __attribute__((ext_vector_type(2)));

template<int N> struct ic { static constexpr int v = N; };

__device__ __forceinline__ v2f lo2(float4 w) { v2f v = {w.x, w.y}; return v; }
__device__ __forceinline__ v2f hi2(float4 w) { v2f v = {w.z, w.w}; return v; }
__device__ __forceinline__ void pkf(v2f& acc, float s, v2f w) {
    v2f ss = {s, s};
    acc = __builtin_elementwise_fma(ss, w, acc);
}
__device__ __forceinline__ float sigmoidf(float v) {
    return 1.0f / (1.0f + expf(-v));
}

// ---- Prologue: build normalized adjacency A (21x21) in fp64, store fp32 ----
__global__ void build_A(const int* __restrict__ ei, const float* __restrict__ ew,
                        float* __restrict__ Aout) {
    __shared__ double deg[NN];
    __shared__ double dinv[NN];
    __shared__ double Asm[NN * NN];
    int t = threadIdx.x;
    for (int k = t; k < NN * NN; k += blockDim.x) Asm[k] = 0.0;
    if (t < NN) deg[t] = 1.0;  // self loop weight 1
    __syncthreads();
    if (t == 0) {
        for (int e = 0; e < EDGES; e++) deg[ei[EDGES + e]] += (double)ew[e];
        for (int i = 0; i < NN; i++) dinv[i] = deg[i] > 0.0 ? 1.0 / sqrt(deg[i]) : 0.0;
        for (int e = 0; e < EDGES; e++) {
            int s = ei[e], d = ei[EDGES + e];
            Asm[d * NN + s] += dinv[s] * (double)ew[e] * dinv[d];
        }
        for (int i = 0; i < NN; i++) Asm[i * NN + i] += dinv[i] * dinv[i];
    }
    __syncthreads();
    for (int k = t; k < NROW * NN; k += blockDim.x)
        Aout[k] = (k < NN * NN) ? (float)Asm[k] : 0.0f;
}

// ---- Prologue: repack bottom halves of (256,128) concat weights ----------
__global__ void pack_bot(const float* __restrict__ w0, const float* __restrict__ w1,
                         float4* __restrict__ out, int ngate) {
    int t = blockIdx.x * blockDim.x + threadIdx.x;
    int per_c = ngate * 128;
    int total = 32 * per_c;
    if (t >= total) return;
    int c = t / per_c, rem = t - c * per_c;
    int gate = rem >> 7;
    int r2 = rem & 127;
    int k2 = r2 >> 6;
    int f0 = r2 & 63;
    int k = 4 * c + 2 * k2;
    const float* src = (gate == 0) ? w0 : w1;
    float4 v;
    v.x = src[(128 + k) * 128 + f0];
    v.y = src[(128 + k) * 128 + f0 + 64];
    v.z = src[(128 + k + 1) * 128 + f0];
    v.w = src[(128 + k + 1) * 128 + f0 + 64];
    out[t] = v;
}

// ---- Prologue: Weff2_g = Wg_2 @ lgw_2_top, pair-interleaved, fp64 accum ----
__global__ void make_weff2(const float* __restrict__ Wz2, const float* __restrict__ Wr2,
                           const float* __restrict__ Wh2,
                           const float* __restrict__ lzw2, const float* __restrict__ lrw2,
                           const float* __restrict__ lhw2,
                           float4* __restrict__ out) {
    int t = blockIdx.x * blockDim.x + threadIdx.x;
    if (t >= 32 * 384) return;
    int c = t / 384, rem = t - c * 384;
    int g = rem >> 7;
    int r2 = rem & 127;
    int k2 = r2 >> 6;
    int f0 = r2 & 63;
    int k = 4 * c + 2 * k2;
    const float* W = (g == 0) ? Wz2 : (g == 1) ? Wr2 : Wh2;
    const float* L = (g == 0) ? lzw2 : (g == 1) ? lrw2 : lhw2;
    double a0 = 0, a1 = 0, a2 = 0, a3 = 0;
    for (int m = 0; m < 128; m++) {
        double w0 = (double)W[k * 128 + m];
        double w1 = (double)W[(k + 1) * 128 + m];
        a0 += w0 * (double)L[m * 128 + f0];
        a1 += w0 * (double)L[m * 128 + f0 + 64];
        a2 += w1 * (double)L[m * 128 + f0];
        a3 += w1 * (double)L[m * 128 + f0 + 64];
    }
    out[t] = make_float4((float)a0, (float)a1, (float)a2, (float)a3);
}

// ---- Prologue: layer-1 effective row vectors + all bias consts (fp64) ----
__global__ void make_vecs(const float* __restrict__ Wz1, const float* __restrict__ Wr1,
                          const float* __restrict__ Wh1,
                          const float* __restrict__ bz1, const float* __restrict__ br1,
                          const float* __restrict__ bh1,
                          const float* __restrict__ lzw1, const float* __restrict__ lrw1,
                          const float* __restrict__ lhw1,
                          const float* __restrict__ lzb1, const float* __restrict__ lrb1,
                          const float* __restrict__ lhb1,
                          const float* __restrict__ bz2, const float* __restrict__ br2,
                          const float* __restrict__ bh2,
                          const float* __restrict__ lzw2, const float* __restrict__ lrw2,
                          const float* __restrict__ lhw2,
                          const float* __restrict__ lzb2, const float* __restrict__ lrb2,
                          const float* __restrict__ lhb2,
                          float* __restrict__ out) {
    int t = blockIdx.x * blockDim.x + threadIdx.x;
    if (t >= 9 * 128) return;
    int v = t >> 7, f = t & 127;
    double acc = 0.0;
    if (v < 3) {
        const float* W = (v == 0) ? Wz1 : (v == 1) ? Wr1 : Wh1;
        const float* L = (v == 0) ? lzw1 : (v == 1) ? lrw1 : lhw1;
        for (int m = 0; m < 128; m++) acc += (double)W[m] * (double)L[m * 128 + f];
    } else if (v < 6) {
        int g = v - 3;
        const float* bb = (g == 0) ? bz1 : (g == 1) ? br1 : bh1;
        const float* L  = (g == 0) ? lzw1 : (g == 1) ? lrw1 : lhw1;
        const float* lb = (g == 0) ? lzb1 : (g == 1) ? lrb1 : lhb1;
        for (int m = 0; m < 128; m++) acc += (double)bb[m] * (double)L[m * 128 + f];
        acc += (double)lb[f];
    } else {
        int g = v - 6;
        const float* bb = (g == 0) ? bz2 : (g == 1) ? br2 : bh2;
        const float* L  = (g == 0) ? lzw2 : (g == 1) ? lrw2 : lhw2;
        const float* lb = (g == 0) ? lzb2 : (g == 1) ? lrb2 : lhb2;
        for (int m = 0; m < 128; m++) acc += (double)bb[m] * (double)L[m * 128 + f];
        acc += (double)lb[f];
    }
    out[t] = (float)acc;
}

// ---- Main: one block per batch, layer-pipelined groups, 2 barriers/tick ----
__global__ __launch_bounds__(NTHREADS, 1) void tgcn_main(
    const float* __restrict__ x,       // (64,500,21)
    const float* __restrict__ ws,
    const float* __restrict__ cls_w,   // (128,1)
    const float* __restrict__ cls_b,   // (1,)
    float* __restrict__ out)           // (64,)
{
    const int b  = blockIdx.x;
    const int t  = threadIdx.x;
    const bool isA = (t < 256);                              // wave-uniform
    const int lt = t & 255;
    const int gw = __builtin_amdgcn_readfirstlane(lt >> 6);  // wave in group 0..3
    const int lane = t & 63;
    const int p  = lane & 7;          // pair slot
    const int rg = lane >> 3;         // row group 0..7
    const int rb = rg * RPT;          // first row of this lane
    const int f0A = gw * 16 + p;      // first pair:  cols (f0A, f0A+64)
    const int f0B = f0A + 8;          // second pair: cols (f0B, f0B+64)

    __shared__ __align__(16) float sH1[2][NROW * S];  // double-buffered
    __shared__ __align__(16) float sH2[NROW * S];
    __shared__ __align__(16) float sHR1[NROW * S];
    __shared__ __align__(16) float sHR2[NROW * S];
    __shared__ __align__(16) float sAH[NROW * S];
    __shared__ float sA[NROW * NN];
    __shared__ float sVec[9 * 128];
    __shared__ float sax[2][NROW];
    __shared__ double sredD[HID];
    __shared__ double sredE[HID];

    const float4* Lzr1 = (const float4*)(ws + WS_LZR1);
    const float4* Lh1  = (const float4*)(ws + WS_LH1);
    const float4* We2  = (const float4*)(ws + WS_WE2);
    const float4* Lzr2 = (const float4*)(ws + WS_LZR2);
    const float4* Lh2  = (const float4*)(ws + WS_LH2);

    const float4* HR1v = (const float4*)sHR1;
    const float4* HR2v = (const float4*)sHR2;
    const float4* AHv  = (const float4*)sAH;
    const float4* H2v  = (const float4*)sH2;

    for (int k = t; k < 2 * NROW * S; k += NTHREADS) ((float*)sH1)[k] = 0.0f;
    for (int k = t; k < NROW * S; k += NTHREADS) {
        sH2[k] = 0.0f; sHR1[k] = 0.0f; sHR2[k] = 0.0f; sAH[k] = 0.0f;
    }
    for (int k = t; k < NROW * NN; k += NTHREADS) sA[k] = ws[WS_A + k];
    for (int k = t; k < 9 * 128; k += NTHREADS) sVec[k] = ws[WS_VEC + k];

    __syncthreads();

    const float* xb = x + (size_t)b * (TSTEPS * NN);
    if (t < NROW) {  // sax for steps 0 and 1 (slot = s&1)
        float a0s = 0.0f, a1s = 0.0f;
        for (int j = 0; j < NN; j++) {
            a0s = fmaf(sA[t * NN + j], xb[j], a0s);
            a1s = fmaf(sA[t * NN + j], xb[NN + j], a1s);
        }
        sax[0][t] = a0s;
        sax[1][t] = a1s;
    }
    __syncthreads();

    // ---- persistent per-thread state carried across barriers ----
    float axp[RPT];                         // A: P1 -> P2
    v2f zg[RPT][2], h1c[RPT][2];            // A: P1 -> P2
    v2f ph[RPT][2], z2[RPT][2], h2c[RPT][2];// B: P4 -> P5 (crosses b2)
    double oA0 = 0.0, oA1 = 0.0, oB0 = 0.0, oB1 = 0.0;  // B output accum

    // ================= phase lambdas (pipelined weight loads) =================
    // P1 (A): layer-1 z,r gates for step s; reads H1 state s-1 = buf[(s+1)&1]
    // Weight pipeline: 2-c groups, ping-pong (2 x 16 float4).
    auto l1_p1 = [&](int s) {
        const float* H1rd = sH1[(s + 1) & 1];
        const float4* H1c = (const float4*)H1rd;
        #pragma unroll
        for (int r = 0; r < RPT; r++) axp[r] = sax[s & 1][rb + r];
        v2f az[RPT][2], ar[RPT][2];
        {
            const v2f wz1A = {sVec[f0A],       sVec[f0A + 64]};
            const v2f wz1B = {sVec[f0B],       sVec[f0B + 64]};
            const v2f wr1A = {sVec[128 + f0A], sVec[128 + f0A + 64]};
            const v2f wr1B = {sVec[128 + f0B], sVec[128 + f0B + 64]};
            const v2f cz1A = {sVec[384 + f0A], sVec[384 + f0A + 64]};
            const v2f cz1B = {sVec[384 + f0B], sVec[384 + f0B + 64]};
            const v2f cr1A = {sVec[512 + f0A], sVec[512 + f0A + 64]};
            const v2f cr1B = {sVec[512 + f0B], sVec[512 + f0B + 64]};
            #pragma unroll
            for (int r = 0; r < RPT; r++) {
                az[r][0] = __builtin_elementwise_fma((v2f){axp[r], axp[r]}, wz1A, cz1A);
                az[r][1] = __builtin_elementwise_fma((v2f){axp[r], axp[r]}, wz1B, cz1B);
                ar[r][0] = __builtin_elementwise_fma((v2f){axp[r], axp[r]}, wr1A, cr1A);
                ar[r][1] = __builtin_elementwise_fma((v2f){axp[r], axp[r]}, wr1B, cr1B);
            }
        }
        float4 w0[16], w1[16];
        auto ld = [&](float4* w, int c0) {
            #pragma unroll
            for (int cc = 0; cc < 2; cc++) {
                const int c = c0 + cc;
                w[cc * 8 + 0] = Lzr1[c * 256 + f0A];
                w[cc * 8 + 1] = Lzr1[c * 256 + 64 + f0A];
                w[cc * 8 + 2] = Lzr1[c * 256 + 128 + f0A];
                w[cc * 8 + 3] = Lzr1[c * 256 + 192 + f0A];
                w[cc * 8 + 4] = Lzr1[c * 256 + f0B];
                w[cc * 8 + 5] = Lzr1[c * 256 + 64 + f0B];
                w[cc * 8 + 6] = Lzr1[c * 256 + 128 + f0B];
                w[cc * 8 + 7] = Lzr1[c * 256 + 192 + f0B];
            }
        };
        auto cp = [&](const float4* w, int c0) {
            #pragma unroll
            for (int cc = 0; cc < 2; cc++) {
                const int c = c0 + cc;
                const float4 wz0A = w[cc * 8 + 0], wz1A = w[cc * 8 + 1];
                const float4 wr0A = w[cc * 8 + 2], wr1A = w[cc * 8 + 3];
                const float4 wz0B = w[cc * 8 + 4], wz1B = w[cc * 8 + 5];
                const float4 wr0B = w[cc * 8 + 6], wr1B = w[cc * 8 + 7];
                #pragma unroll
                for (int r = 0; r < RPT; r++) {
                    const float4 h = H1c[(rb + r) * SV4 + c];
                    pkf(az[r][0], h.x, lo2(wz0A)); pkf(az[r][0], h.y, hi2(wz0A));
                    pkf(az[r][0], h.z, lo2(wz1A)); pkf(az[r][0], h.w, hi2(wz1A));
                    pkf(ar[r][0], h.x, lo2(wr0A)); pkf(ar[r][0], h.y, hi2(wr0A));
                    pkf(ar[r][0], h.z, lo2(wr1A)); pkf(ar[r][0], h.w, hi2(wr1A));
                    pkf(az[r][1], h.x, lo2(wz0B)); pkf(az[r][1], h.y, hi2(wz0B));
                    pkf(az[r][1], h.z, lo2(wz1B)); pkf(az[r][1], h.w, hi2(wz1B));
                    pkf(ar[r][1], h.x, lo2(wr0B)); pkf(ar[r][1], h.y, hi2(wr0B));
                    pkf(ar[r][1], h.z, lo2(wr1B)); pkf(ar[r][1], h.w, hi2(wr1B));
                }
            }
        };
        ld(w0, 0);
        for (int cb = 0; cb < 32; cb += 4) {
            ld(w1, cb + 2);
            cp(w0, cb);
            if (cb + 4 < 32) ld(w0, cb + 4);
            cp(w1, cb + 2);
        }
        #pragma unroll
        for (int r = 0; r < RPT; r++) {
            const int row = rb + r;
            zg[r][0].x = sigmoidf(az[r][0].x);
            zg[r][0].y = sigmoidf(az[r][0].y);
            zg[r][1].x = sigmoidf(az[r][1].x);
            zg[r][1].y = sigmoidf(az[r][1].y);
            const float rA0 = sigmoidf(ar[r][0].x);
            const float rA1 = sigmoidf(ar[r][0].y);
            const float rB0 = sigmoidf(ar[r][1].x);
            const float rB1 = sigmoidf(ar[r][1].y);
            h1c[r][0].x = H1rd[row * S + f0A];
            h1c[r][0].y = H1rd[row * S + f0A + 64];
            h1c[r][1].x = H1rd[row * S + f0B];
            h1c[r][1].y = H1rd[row * S + f0B + 64];
            sHR1[row * S + f0A]      = h1c[r][0].x * rA0;
            sHR1[row * S + f0A + 64] = h1c[r][0].y * rA1;
            sHR1[row * S + f0B]      = h1c[r][1].x * rB0;
            sHR1[row * S + f0B + 64] = h1c[r][1].y * rB1;
        }
    };

    // P2 (A): layer-1 h gate + H1 update. Weight pipeline: 4-c groups.
    auto l1_p2 = [&](int s) {
        float* H1wr = sH1[s & 1];
        v2f ah[RPT][2];
        {
            const v2f wh1A = {sVec[256 + f0A], sVec[256 + f0A + 64]};
            const v2f wh1B = {sVec[256 + f0B], sVec[256 + f0B + 64]};
            const v2f ch1A = {sVec[640 + f0A], sVec[640 + f0A + 64]};
            const v2f ch1B = {sVec[640 + f0B], sVec[640 + f0B + 64]};
            #pragma unroll
            for (int r = 0; r < RPT; r++) {
                ah[r][0] = __builtin_elementwise_fma((v2f){axp[r], axp[r]}, wh1A, ch1A);
                ah[r][1] = __builtin_elementwise_fma((v2f){axp[r], axp[r]}, wh1B, ch1B);
            }
        }
        float4 w0[16], w1[16];
        auto ld = [&](float4* w, int c0) {
            #pragma unroll
            for (int cc = 0; cc < 4; cc++) {
                const int c = c0 + cc;
                w[cc * 4 + 0] = Lh1[c * 128 + f0A];
                w[cc * 4 + 1] = Lh1[c * 128 + 64 + f0A];
                w[cc * 4 + 2] = Lh1[c * 128 + f0B];
                w[cc * 4 + 3] = Lh1[c * 128 + 64 + f0B];
            }
        };
        auto cp = [&](const float4* w, int c0) {
            #pragma unroll
            for (int cc = 0; cc < 4; cc++) {
                const int c = c0 + cc;
                const float4 wh0A = w[cc * 4 + 0], wh1A = w[cc * 4 + 1];
                const float4 wh0B = w[cc * 4 + 2], wh1B = w[cc * 4 + 3];
                #pragma unroll
                for (int r = 0; r < RPT; r++) {
                    const float4 q = HR1v[(rb + r) * SV4 + c];
                    pkf(ah[r][0], q.x, lo2(wh0A)); pkf(ah[r][0], q.y, hi2(wh0A));
                    pkf(ah[r][0], q.z, lo2(wh1A)); pkf(ah[r][0], q.w, hi2(wh1A));
                    pkf(ah[r][1], q.x, lo2(wh0B)); pkf(ah[r][1], q.y, hi2(wh0B));
                    pkf(ah[r][1], q.z, lo2(wh1B)); pkf(ah[r][1], q.w, hi2(wh1B));
                }
            }
        };
        ld(w0, 0);
        for (int cb = 0; cb < 32; cb += 8) {
            ld(w1, cb + 4);
            cp(w0, cb);
            if (cb + 8 < 32) ld(w0, cb + 8);
            cp(w1, cb + 4);
        }
        #pragma unroll
        for (int r = 0; r < RPT; r++) {
            const int row = rb + r;
            const float n0 = fmaf(zg[r][0].x, h1c[r][0].x, (1.0f - zg[r][0].x) * tanhf(ah[r][0].x));
            const float n1 = fmaf(zg[r][0].y, h1c[r][0].y, (1.0f - zg[r][0].y) * tanhf(ah[r][0].y));
            const float n2 = fmaf(zg[r][1].x, h1c[r][1].x, (1.0f - zg[r][1].x) * tanhf(ah[r][1].x));
            const float n3 = fmaf(zg[r][1].y, h1c[r][1].y, (1.0f - zg[r][1].y) * tanhf(ah[r][1].y));
            H1wr[row * S + f0A]      = n0;
            H1wr[row * S + f0A + 64] = n1;
            H1wr[row * S + f0B]      = n2;
            H1wr[row * S + f0B + 64] = n3;
        }
    };

    // P3 (B): AH = A @ H1(state tt) for own rows/cols (LDS only)
    auto l2_p3 = [&](int tt) {
        const float* H1rd = sH1[tt & 1];
        v2f aa[RPT][2];
        #pragma unroll
        for (int r = 0; r < RPT; r++) { aa[r][0] = (v2f){0.0f, 0.0f}; aa[r][1] = (v2f){0.0f, 0.0f}; }
        #pragma unroll 3
        for (int j = 0; j < NN; j++) {
            const v2f hjA = {H1rd[j * S + f0A], H1rd[j * S + f0A + 64]};
            const v2f hjB = {H1rd[j * S + f0B], H1rd[j * S + f0B + 64]};
            #pragma unroll
            for (int r = 0; r < RPT; r++) {
                const float arj = sA[(rb + r) * NN + j];
                aa[r][0] = __builtin_elementwise_fma((v2f){arj, arj}, hjA, aa[r][0]);
                aa[r][1] = __builtin_elementwise_fma((v2f){arj, arj}, hjB, aa[r][1]);
            }
        }
        #pragma unroll
        for (int r = 0; r < RPT; r++) {
            const int row = rb + r;
            sAH[row * S + f0A]      = aa[r][0].x;
            sAH[row * S + f0A + 64] = aa[r][0].y;
            sAH[row * S + f0B]      = aa[r][1].x;
            sAH[row * S + f0B + 64] = aa[r][1].y;
        }
    };

    // P4 (B): layer-2 gcn + z,r gates; h-gate a-chunk partials into ph.
    // Two per-pair passes; each pass: 1-c ping-pong groups (2 x 10 float4).
    // Chains stay c-ascending, a-chunk-then-q-chunk per gate -> bit-exact.
    auto l2_p4 = [&]() {
        v2f pz[RPT][2], pr[RPT][2];
        {
            const v2f cz2A = {sVec[768 + f0A],  sVec[768 + f0A + 64]};
            const v2f cz2B = {sVec[768 + f0B],  sVec[768 + f0B + 64]};
            const v2f cr2A = {sVec[896 + f0A],  sVec[896 + f0A + 64]};
            const v2f cr2B = {sVec[896 + f0B],  sVec[896 + f0B + 64]};
            const v2f ch2A = {sVec[1024 + f0A], sVec[1024 + f0A + 64]};
            const v2f ch2B = {sVec[1024 + f0B], sVec[1024 + f0B + 64]};
            #pragma unroll
            for (int r = 0; r < RPT; r++) {
                pz[r][0] = cz2A; pz[r][1] = cz2B;
                pr[r][0] = cr2A; pr[r][1] = cr2B;
                ph[r][0] = ch2A; ph[r][1] = ch2B;
            }
        }
        auto pass = [&](auto pc) {
            constexpr int P = decltype(pc)::v;
            const int f0 = P ? f0B : f0A;
            float4 w0[10], w1[10];
            auto ld = [&](float4* w, int c) {
                w[0] = We2[c * 384 + f0];
                w[1] = We2[c * 384 + 64 + f0];
                w[2] = We2[c * 384 + 128 + f0];
                w[3] = We2[c * 384 + 192 + f0];
                w[4] = We2[c * 384 + 256 + f0];
                w[5] = We2[c * 384 + 320 + f0];
                w[6] = Lzr2[c * 256 + f0];
                w[7] = Lzr2[c * 256 + 64 + f0];
                w[8] = Lzr2[c * 256 + 128 + f0];
                w[9] = Lzr2[c * 256 + 192 + f0];
            };
            auto cp = [&](const float4* w, int c) {
                const float4 wz0 = w[0], wz1 = w[1], wr0 = w[2], wr1 = w[3];
                const float4 wh0 = w[4], wh1 = w[5];
                const float4 lz0 = w[6], lz1 = w[7], lr0 = w[8], lr1 = w[9];
                #pragma unroll
                for (int r = 0; r < RPT; r++) {
                    const float4 a = AHv[(rb + r) * SV4 + c];
                    const float4 q = H2v[(rb + r) * SV4 + c];
                    pkf(pz[r][P], a.x, lo2(wz0)); pkf(pz[r][P], a.y, hi2(wz0));
                    pkf(pz[r][P], a.z, lo2(wz1)); pkf(pz[r][P], a.w, hi2(wz1));
                    pkf(pz[r][P], q.x, lo2(lz0)); pkf(pz[r][P], q.y, hi2(lz0));
                    pkf(pz[r][P], q.z, lo2(lz1)); pkf(pz[r][P], q.w, hi2(lz1));
                    pkf(pr[r][P], a.x, lo2(wr0)); pkf(pr[r][P], a.y, hi2(wr0));
                    pkf(pr[r][P], a.z, lo2(wr1)); pkf(pr[r][P], a.w, hi2(wr1));
                    pkf(pr[r][P], q.x, lo2(lr0)); pkf(pr[r][P], q.y, hi2(lr0));
                    pkf(pr[r][P], q.z, lo2(lr1)); pkf(pr[r][P], q.w, hi2(lr1));
                    pkf(ph[r][P], a.x, lo2(wh0)); pkf(ph[r][P], a.y, hi2(wh0));
                    pkf(ph[r][P], a.z, lo2(wh1)); pkf(ph[r][P], a.w, hi2(wh1));
                }
            };
            ld(w0, 0);
            for (int c = 0; c < 32; c += 2) {
                ld(w1, c + 1);
                cp(w0, c);
                if (c + 2 < 32) ld(w0, c + 2);
                cp(w1, c + 1);
            }
        };
        pass(ic<0>{});
        pass(ic<1>{});
        #pragma unroll
        for (int r = 0; r < RPT; r++) {
            const int row = rb + r;
            z2[r][0].x = sigmoidf(pz[r][0].x);
            z2[r][0].y = sigmoidf(pz[r][0].y);
            z2[r][1].x = sigmoidf(pz[r][1].x);
            z2[r][1].y = sigmoidf(pz[r][1].y);
            const float rA0 = sigmoidf(pr[r][0].x);
            const float rA1 = sigmoidf(pr[r][0].y);
            const float rB0 = sigmoidf(pr[r][1].x);
            const float rB1 = sigmoidf(pr[r][1].y);
            h2c[r][0].x = sH2[row * S + f0A];
            h2c[r][0].y = sH2[row * S + f0A + 64];
            h2c[r][1].x = sH2[row * S + f0B];
            h2c[r][1].y = sH2[row * S + f0B + 64];
            sHR2[row * S + f0A]      = h2c[r][0].x * rA0;
            sHR2[row * S + f0A + 64] = h2c[r][0].y * rA1;
            sHR2[row * S + f0B]      = h2c[r][1].x * rB0;
            sHR2[row * S + f0B + 64] = h2c[r][1].y * rB1;
        }
    };

    // P5 (B): layer-2 h gate finish + H2 update + output accum.
    // Weight pipeline: 4-c groups.
    auto l2_p5 = [&]() {
        float4 w0[16], w1[16];
        auto ld = [&](float4* w, int c0) {
            #pragma unroll
            for (int cc = 0; cc < 4; cc++) {
                const int c = c0 + cc;
                w[cc * 4 + 0] = Lh2[c * 128 + f0A];
                w[cc * 4 + 1] = Lh2[c * 128 + 64 + f0A];
                w[cc * 4 + 2] = Lh2[c * 128 + f0B];
                w[cc * 4 + 3] = Lh2[c * 128 + 64 + f0B];
            }
        };
        auto cp = [&](const float4* w, int c0) {
            #pragma unroll
            for (int cc = 0; cc < 4; cc++) {
                const int c = c0 + cc;
                const float4 lh0A = w[cc * 4 + 0], lh1A = w[cc * 4 + 1];
                const float4 lh0B = w[cc * 4 + 2], lh1B = w[cc * 4 + 3];
                #pragma unroll
                for (int r = 0; r < RPT; r++) {
                    const float4 q = HR2v[(rb + r) * SV4 + c];
                    pkf(ph[r][0], q.x, lo2(lh0A)); pkf(ph[r][0], q.y, hi2(lh0A));
                    pkf(ph[r][0], q.z, lo2(lh1A)); pkf(ph[r][0], q.w, hi2(lh1A));
                    pkf(ph[r][1], q.x, lo2(lh0B)); pkf(ph[r][1], q.y, hi2(lh0B));
                    pkf(ph[r][1], q.z, lo2(lh1B)); pkf(ph[r][1], q.w, hi2(lh1B));
                }
            }
        };
        ld(w0, 0);
        for (int cb = 0; cb < 32; cb += 8) {
            ld(w1, cb + 4);
            cp(w0, cb);
            if (cb + 8 < 32) ld(w0, cb + 8);
            cp(w1, cb + 4);
        }
        #pragma unroll
        for (int r = 0; r < RPT; r++) {
            const int row = rb + r;
            const float mA0 = fmaf(z2[r][0].x, h2c[r][0].x, (1.0f - z2[r][0].x) * tanhf(ph[r][0].x));
            const float mA1 = fmaf(z2[r][0].y, h2c[r][0].y, (1.0f - z2[r][0].y) * tanhf(ph[r][0].y));
            const float mB0 = fmaf(z2[r][1].x, h2c[r][1].x, (1.0f - z2[r][1].x) * tanhf(ph[r][1].x));
            const float mB1 = fmaf(z2[r][1].y, h2c[r][1].y, (1.0f - z2[r][1].y) * tanhf(ph[r][1].y));
            sH2[row * S + f0A]      = mA0;
            sH2[row * S + f0A + 64] = mA1;
            sH2[row * S + f0B]      = mB0;
            sH2[row * S + f0B + 64] = mB1;
            if (row < NN) {
                oA0 += (double)mA0; oA1 += (double)mA1;
                oB0 += (double)mB0; oB1 += (double)mB1;
            }
        }
    };

    // ======== pipeline prologue: A computes step 0 ========
    if (isA) l1_p1(0);
    __syncthreads();
    if (isA) l1_p2(0);
    __syncthreads();

    // ======== main ticks: 2 barriers each ========
    for (int k = 0; k < TSTEPS; k++) {
        // alpha
        if (isA) {
            if (k + 1 < TSTEPS) l1_p1(k + 1);
        } else {
            if (k >= 1) l2_p5();     // finish step k-1
            l2_p3(k);
        }
        __syncthreads();  // b1: publishes sHR1(k+1), sAH(k), sH2(k-1)
        // beta
        if (isA) {
            if (k + 1 < TSTEPS) l1_p2(k + 1);
            if (t < NROW && k + 2 < TSTEPS) {   // sax prefetch for step k+2
                const float* xt = xb + (size_t)(k + 2) * NN;
                float a = 0.0f;
                for (int j = 0; j < NN; j++) a = fmaf(sA[t * NN + j], xt[j], a);
                sax[(k + 2) & 1][t] = a;
            }
        } else {
            l2_p4();
        }
        __syncthreads();  // b2: publishes H1(k+1), sHR2(k), sax(k+2)
    }

    // ---------- Epilogue: finish step T-1, mean over (T, nodes), cls ----------
    if (!isA) {
        l2_p5();  // step T-1 (sHR2 published at final b2)
        double vA0 = oA0, vA1 = oA1, vB0 = oB0, vB1 = oB1;
        #pragma unroll
        for (int off = 32; off >= 8; off >>= 1) {
            vA0 += __shfl_down(vA0, off, 64);
            vA1 += __shfl_down(vA1, off, 64);
            vB0 += __shfl_down(vB0, off, 64);
            vB1 += __shfl_down(vB1, off, 64);
        }
        if (rg == 0) {   // lane p of each B wave owns 4 columns
            sredD[f0A]      = vA0;
            sredD[f0A + 64] = vA1;
            sredD[f0B]      = vB0;
            sredD[f0B + 64] = vB1;
        }
    }
    __syncthreads();
    if (t < HID) {
        sredE[t] = (sredD[t] / (double)(TSTEPS * NN)) * (double)cls_w[t];
    }
    __syncthreads();
    if (t < 64) {
        double v = sredE[t] + sredE[t + 64];
        for (int off = 32; off; off >>= 1) v += __shfl_down(v, off, 64);
        if (t == 0) out[b] = (float)(v + (double)cls_b[0]);
    }
}

extern "C" void kernel_launch(void* const* d_in, const int* in_sizes, int n_in,
                              void* d_out, int out_size, void* d_ws, size_t ws_size,
                              hipStream_t stream) {
    const float* x    = (const float*)d_in[0];
    const int*   ei   = (const int*)  d_in[1];
    const float* ew   = (const float*)d_in[2];
    const float* Wz1  = (const float*)d_in[3];
    const float* bz1  = (const float*)d_in[4];
    const float* lzw1 = (const float*)d_in[5];
    const float* lzb1 = (const float*)d_in[6];
    const float* Wr1  = (const float*)d_in[7];
    const float* br1  = (const float*)d_in[8];
    const float* lrw1 = (const float*)d_in[9];
    const float* lrb1 = (const float*)d_in[10];
    const float* Wh1  = (const float*)d_in[11];
    const float* bh1  = (const float*)d_in[12];
    const float* lhw1 = (const float*)d_in[13];
    const float* lhb1 = (const float*)d_in[14];
    const float* Wz2  = (const float*)d_in[15];
    const float* bz2  = (const float*)d_in[16];
    const float* lzw2 = (const float*)d_in[17];
    const float* lzb2 = (const float*)d_in[18];
    const float* Wr2  = (const float*)d_in[19];
    const float* br2  = (const float*)d_in[20];
    const float* lrw2 = (const float*)d_in[21];
    const float* lrb2 = (const float*)d_in[22];
    const float* Wh2  = (const float*)d_in[23];
    const float* bh2  = (const float*)d_in[24];
    const float* lhw2 = (const float*)d_in[25];
    const float* lhb2 = (const float*)d_in[26];
    const float* clsw = (const float*)d_in[27];
    const float* clsb = (const float*)d_in[28];

    float* ws   = (float*)d_ws;
    float* outp = (float*)d_out;

    build_A<<<1, 64, 0, stream>>>(ei, ew, ws + WS_A);
    pack_bot<<<32, 256, 0, stream>>>(lzw1, lrw1, (float4*)(ws + WS_LZR1), 2);
    pack_bot<<<16, 256, 0, stream>>>(lhw1, lhw1, (float4*)(ws + WS_LH1), 1);
    pack_bot<<<32, 256, 0, stream>>>(lzw2, lrw2, (float4*)(ws + WS_LZR2), 2);
    pack_bot<<<16, 256, 0, stream>>>(lhw2, lhw2, (float4*)(ws + WS_LH2), 1);
    make_weff2<<<48, 256, 0, stream>>>(Wz2, Wr2, Wh2, lzw2, lrw2, lhw2,
                                       (float4*)(ws + WS_WE2));
    make_vecs<<<5, 256, 0, stream>>>(Wz1, Wr1, Wh1, bz1, br1, bh1,
                                     lzw1, lrw1, lhw1, lzb1, lrb1, lhb1,
                                     bz2, br2, bh2, lzw2, lrw2, lhw2,
                                     lzb2, lrb2, lhb2, ws + WS_VEC);
    tgcn_main<<<64, NTHREADS, 0, stream>>>(x, ws, clsw, clsb, outp);
}

// Round 5
// 41688.861 us; speedup vs baseline: 3.2444x; 1.0100x over previous
//
#include <hip/hip_runtime.h>
#include <hip/hip_bf16.h>

// TGCN: B=64, T=500, N=21, HID=128.
// Round 12: SROA fix. Rounds 9-11's ping-pong buffers were LOCAL ARRAYS
// passed BY POINTER into lambdas -> address-taken -> allocated in scratch
// (GB-scale FETCH/WRITE, VGPR stuck at 128, VALUBusy 8%). This round:
// named-member structs passed/returned BY VALUE (P1W/P2W/P4W), ping-pong by
// struct assignment -> SROA promotes to VGPRs. Same load order, same
// accumulation chain order (c-ascending, identical intra-c sequence) ->
// bit-exact (absmax 0.0). __launch_bounds__(512,2): 512-thread block is
// geometrically 2 waves/SIMD -> 256-VGPR budget.
// NEVER reorder per-element sums in the recurrence.

#define NN 21
#define NROW 24            // padded rows (21,22,23 zero)
#define S 132              // padded float stride for H arrays (132%32==4)
#define SV4 33             // float4 stride
#define HID 128
#define TSTEPS 500
#define EDGES 210
#define NTHREADS 512       // 8 waves: 4 per group
#define RPT 3              // rows per row-group

// ws layout (float offsets) — unchanged
#define WS_A     0
#define WS_VEC   1600
#define WS_LZR1  3200
#define WS_LH1   36000
#define WS_WE2   52400
#define WS_LZR2  101600
#define WS_LH2   134400

typedef float v2f __attribute__((ext_vector_type(2)));

template<int N> struct ic { static constexpr int v = N; };

struct P1W { float4 zA0, zA1, rA0, rA1, zB0, zB1, rB0, rB1; };   // one c, P1
struct P2W { float4 h0A, h1A, h0B, h1B; };                       // one c, P2/P5
struct P2G { P2W c0, c1, c2, c3; };                              // 4-c group
struct P4W { float4 wz0, wz1, wr0, wr1, wh0, wh1, lz0, lz1, lr0, lr1; }; // one c, P4

__device__ __forceinline__ v2f lo2(float4 w) { v2f v = {w.x, w.y}; return v; }
__device__ __forceinline__ v2f hi2(float4 w) { v2f v = {w.z, w.w}; return v; }
__device__ __forceinline__ void pkf(v2f& acc, float s, v2f w) {
    v2f ss = {s, s};
    acc = __builtin_elementwise_fma(ss, w, acc);
}
__device__ __forceinline__ float sigmoidf(float v) {
    return 1.0f / (1.0f + expf(-v));
}

// ---- Prologue: build normalized adjacency A (21x21) in fp64, store fp32 ----
__global__ void build_A(const int* __restrict__ ei, const float* __restrict__ ew,
                        float* __restrict__ Aout) {
    __shared__ double deg[NN];
    __shared__ double dinv[NN];
    __shared__ double Asm[NN * NN];
    int t = threadIdx.x;
    for (int k = t; k < NN * NN; k += blockDim.x) Asm[k] = 0.0;
    if (t < NN) deg[t] = 1.0;  // self loop weight 1
    __syncthreads();
    if (t == 0) {
        for (int e = 0; e < EDGES; e++) deg[ei[EDGES + e]] += (double)ew[e];
        for (int i = 0; i < NN; i++) dinv[i] = deg[i] > 0.0 ? 1.0 / sqrt(deg[i]) : 0.0;
        for (int e = 0; e < EDGES; e++) {
            int s = ei[e], d = ei[EDGES + e];
            Asm[d * NN + s] += dinv[s] * (double)ew[e] * dinv[d];
        }
        for (int i = 0; i < NN; i++) Asm[i * NN + i] += dinv[i] * dinv[i];
    }
    __syncthreads();
    for (int k = t; k < NROW * NN; k += blockDim.x)
        Aout[k] = (k < NN * NN) ? (float)Asm[k] : 0.0f;
}

// ---- Prologue: repack bottom halves of (256,128) concat weights ----------
__global__ void pack_bot(const float* __restrict__ w0, const float* __restrict__ w1,
                         float4* __restrict__ out, int ngate) {
    int t = blockIdx.x * blockDim.x + threadIdx.x;
    int per_c = ngate * 128;
    int total = 32 * per_c;
    if (t >= total) return;
    int c = t / per_c, rem = t - c * per_c;
    int gate = rem >> 7;
    int r2 = rem & 127;
    int k2 = r2 >> 6;
    int f0 = r2 & 63;
    int k = 4 * c + 2 * k2;
    const float* src = (gate == 0) ? w0 : w1;
    float4 v;
    v.x = src[(128 + k) * 128 + f0];
    v.y = src[(128 + k) * 128 + f0 + 64];
    v.z = src[(128 + k + 1) * 128 + f0];
    v.w = src[(128 + k + 1) * 128 + f0 + 64];
    out[t] = v;
}

// ---- Prologue: Weff2_g = Wg_2 @ lgw_2_top, pair-interleaved, fp64 accum ----
__global__ void make_weff2(const float* __restrict__ Wz2, const float* __restrict__ Wr2,
                           const float* __restrict__ Wh2,
                           const float* __restrict__ lzw2, const float* __restrict__ lrw2,
                           const float* __restrict__ lhw2,
                           float4* __restrict__ out) {
    int t = blockIdx.x * blockDim.x + threadIdx.x;
    if (t >= 32 * 384) return;
    int c = t / 384, rem = t - c * 384;
    int g = rem >> 7;
    int r2 = rem & 127;
    int k2 = r2 >> 6;
    int f0 = r2 & 63;
    int k = 4 * c + 2 * k2;
    const float* W = (g == 0) ? Wz2 : (g == 1) ? Wr2 : Wh2;
    const float* L = (g == 0) ? lzw2 : (g == 1) ? lrw2 : lhw2;
    double a0 = 0, a1 = 0, a2 = 0, a3 = 0;
    for (int m = 0; m < 128; m++) {
        double w0 = (double)W[k * 128 + m];
        double w1 = (double)W[(k + 1) * 128 + m];
        a0 += w0 * (double)L[m * 128 + f0];
        a1 += w0 * (double)L[m * 128 + f0 + 64];
        a2 += w1 * (double)L[m * 128 + f0];
        a3 += w1 * (double)L[m * 128 + f0 + 64];
    }
    out[t] = make_float4((float)a0, (float)a1, (float)a2, (float)a3);
}

// ---- Prologue: layer-1 effective row vectors + all bias consts (fp64) ----
__global__ void make_vecs(const float* __restrict__ Wz1, const float* __restrict__ Wr1,
                          const float* __restrict__ Wh1,
                          const float* __restrict__ bz1, const float* __restrict__ br1,
                          const float* __restrict__ bh1,
                          const float* __restrict__ lzw1, const float* __restrict__ lrw1,
                          const float* __restrict__ lhw1,
                          const float* __restrict__ lzb1, const float* __restrict__ lrb1,
                          const float* __restrict__ lhb1,
                          const float* __restrict__ bz2, const float* __restrict__ br2,
                          const float* __restrict__ bh2,
                          const float* __restrict__ lzw2, const float* __restrict__ lrw2,
                          const float* __restrict__ lhw2,
                          const float* __restrict__ lzb2, const float* __restrict__ lrb2,
                          const float* __restrict__ lhb2,
                          float* __restrict__ out) {
    int t = blockIdx.x * blockDim.x + threadIdx.x;
    if (t >= 9 * 128) return;
    int v = t >> 7, f = t & 127;
    double acc = 0.0;
    if (v < 3) {
        const float* W = (v == 0) ? Wz1 : (v == 1) ? Wr1 : Wh1;
        const float* L = (v == 0) ? lzw1 : (v == 1) ? lrw1 : lhw1;
        for (int m = 0; m < 128; m++) acc += (double)W[m] * (double)L[m * 128 + f];
    } else if (v < 6) {
        int g = v - 3;
        const float* bb = (g == 0) ? bz1 : (g == 1) ? br1 : bh1;
        const float* L  = (g == 0) ? lzw1 : (g == 1) ? lrw1 : lhw1;
        const float* lb = (g == 0) ? lzb1 : (g == 1) ? lrb1 : lhb1;
        for (int m = 0; m < 128; m++) acc += (double)bb[m] * (double)L[m * 128 + f];
        acc += (double)lb[f];
    } else {
        int g = v - 6;
        const float* bb = (g == 0) ? bz2 : (g == 1) ? br2 : bh2;
        const float* L  = (g == 0) ? lzw2 : (g == 1) ? lrw2 : lhw2;
        const float* lb = (g == 0) ? lzb2 : (g == 1) ? lrb2 : lhb2;
        for (int m = 0; m < 128; m++) acc += (double)bb[m] * (double)L[m * 128 + f];
        acc += (double)lb[f];
    }
    out[t] = (float)acc;
}

// ---- Main: one block per batch, layer-pipelined groups, 2 barriers/tick ----
__global__ __launch_bounds__(NTHREADS, 2) void tgcn_main(
    const float* __restrict__ x,       // (64,500,21)
    const float* __restrict__ ws,
    const float* __restrict__ cls_w,   // (128,1)
    const float* __restrict__ cls_b,   // (1,)
    float* __restrict__ out)           // (64,)
{
    const int b  = blockIdx.x;
    const int t  = threadIdx.x;
    const bool isA = (t < 256);                              // wave-uniform
    const int lt = t & 255;
    const int gw = __builtin_amdgcn_readfirstlane(lt >> 6);  // wave in group 0..3
    const int lane = t & 63;
    const int p  = lane & 7;          // pair slot
    const int rg = lane >> 3;         // row group 0..7
    const int rb = rg * RPT;          // first row of this lane
    const int f0A = gw * 16 + p;      // first pair:  cols (f0A, f0A+64)
    const int f0B = f0A + 8;          // second pair: cols (f0B, f0B+64)

    __shared__ __align__(16) float sH1[2][NROW * S];  // double-buffered
    __shared__ __align__(16) float sH2[NROW * S];
    __shared__ __align__(16) float sHR1[NROW * S];
    __shared__ __align__(16) float sHR2[NROW * S];
    __shared__ __align__(16) float sAH[NROW * S];
    __shared__ float sA[NROW * NN];
    __shared__ float sVec[9 * 128];
    __shared__ float sax[2][NROW];
    __shared__ double sredD[HID];
    __shared__ double sredE[HID];

    const float4* Lzr1 = (const float4*)(ws + WS_LZR1);
    const float4* Lh1  = (const float4*)(ws + WS_LH1);
    const float4* We2  = (const float4*)(ws + WS_WE2);
    const float4* Lzr2 = (const float4*)(ws + WS_LZR2);
    const float4* Lh2  = (const float4*)(ws + WS_LH2);

    const float4* HR1v = (const float4*)sHR1;
    const float4* HR2v = (const float4*)sHR2;
    const float4* AHv  = (const float4*)sAH;
    const float4* H2v  = (const float4*)sH2;

    for (int k = t; k < 2 * NROW * S; k += NTHREADS) ((float*)sH1)[k] = 0.0f;
    for (int k = t; k < NROW * S; k += NTHREADS) {
        sH2[k] = 0.0f; sHR1[k] = 0.0f; sHR2[k] = 0.0f; sAH[k] = 0.0f;
    }
    for (int k = t; k < NROW * NN; k += NTHREADS) sA[k] = ws[WS_A + k];
    for (int k = t; k < 9 * 128; k += NTHREADS) sVec[k] = ws[WS_VEC + k];

    __syncthreads();

    const float* xb = x + (size_t)b * (TSTEPS * NN);
    if (t < NROW) {  // sax for steps 0 and 1 (slot = s&1)
        float a0s = 0.0f, a1s = 0.0f;
        for (int j = 0; j < NN; j++) {
            a0s = fmaf(sA[t * NN + j], xb[j], a0s);
            a1s = fmaf(sA[t * NN + j], xb[NN + j], a1s);
        }
        sax[0][t] = a0s;
        sax[1][t] = a1s;
    }
    __syncthreads();

    // ---- persistent per-thread state carried across barriers ----
    float axp[RPT];                         // A: P1 -> P2
    v2f zg[RPT][2], h1c[RPT][2];            // A: P1 -> P2
    v2f ph[RPT][2], z2[RPT][2], h2c[RPT][2];// B: P4 -> P5 (crosses b2)
    double oA0 = 0.0, oA1 = 0.0, oB0 = 0.0, oB1 = 0.0;  // B output accum

    // ====== SROA-safe weight loaders (structs by value, no local arrays) =====
    auto ldP1 = [&](int c) {
        P1W w;
        w.zA0 = Lzr1[c * 256 + f0A];
        w.zA1 = Lzr1[c * 256 + 64 + f0A];
        w.rA0 = Lzr1[c * 256 + 128 + f0A];
        w.rA1 = Lzr1[c * 256 + 192 + f0A];
        w.zB0 = Lzr1[c * 256 + f0B];
        w.zB1 = Lzr1[c * 256 + 64 + f0B];
        w.rB0 = Lzr1[c * 256 + 128 + f0B];
        w.rB1 = Lzr1[c * 256 + 192 + f0B];
        return w;
    };
    auto ldP2one = [&](const float4* L, int c) {
        P2W w;
        w.h0A = L[c * 128 + f0A];
        w.h1A = L[c * 128 + 64 + f0A];
        w.h0B = L[c * 128 + f0B];
        w.h1B = L[c * 128 + 64 + f0B];
        return w;
    };
    auto ldP2 = [&](const float4* L, int c0) {
        P2G g;
        g.c0 = ldP2one(L, c0);
        g.c1 = ldP2one(L, c0 + 1);
        g.c2 = ldP2one(L, c0 + 2);
        g.c3 = ldP2one(L, c0 + 3);
        return g;
    };
    auto ldP4 = [&](int c, int f0) {
        P4W w;
        w.wz0 = We2[c * 384 + f0];
        w.wz1 = We2[c * 384 + 64 + f0];
        w.wr0 = We2[c * 384 + 128 + f0];
        w.wr1 = We2[c * 384 + 192 + f0];
        w.wh0 = We2[c * 384 + 256 + f0];
        w.wh1 = We2[c * 384 + 320 + f0];
        w.lz0 = Lzr2[c * 256 + f0];
        w.lz1 = Lzr2[c * 256 + 64 + f0];
        w.lr0 = Lzr2[c * 256 + 128 + f0];
        w.lr1 = Lzr2[c * 256 + 192 + f0];
        return w;
    };

    // ================= phase lambdas (pipelined weight loads) =================
    // P1 (A): layer-1 z,r gates for step s; reads H1 state s-1 = buf[(s+1)&1]
    // Weight pipeline: 2-c groups, ping-pong (2 x 2 P1W).
    auto l1_p1 = [&](int s) {
        const float* H1rd = sH1[(s + 1) & 1];
        const float4* H1c = (const float4*)H1rd;
        #pragma unroll
        for (int r = 0; r < RPT; r++) axp[r] = sax[s & 1][rb + r];
        v2f az[RPT][2], ar[RPT][2];
        {
            const v2f wz1A = {sVec[f0A],       sVec[f0A + 64]};
            const v2f wz1B = {sVec[f0B],       sVec[f0B + 64]};
            const v2f wr1A = {sVec[128 + f0A], sVec[128 + f0A + 64]};
            const v2f wr1B = {sVec[128 + f0B], sVec[128 + f0B + 64]};
            const v2f cz1A = {sVec[384 + f0A], sVec[384 + f0A + 64]};
            const v2f cz1B = {sVec[384 + f0B], sVec[384 + f0B + 64]};
            const v2f cr1A = {sVec[512 + f0A], sVec[512 + f0A + 64]};
            const v2f cr1B = {sVec[512 + f0B], sVec[512 + f0B + 64]};
            #pragma unroll
            for (int r = 0; r < RPT; r++) {
                az[r][0] = __builtin_elementwise_fma((v2f){axp[r], axp[r]}, wz1A, cz1A);
                az[r][1] = __builtin_elementwise_fma((v2f){axp[r], axp[r]}, wz1B, cz1B);
                ar[r][0] = __builtin_elementwise_fma((v2f){axp[r], axp[r]}, wr1A, cr1A);
                ar[r][1] = __builtin_elementwise_fma((v2f){axp[r], axp[r]}, wr1B, cr1B);
            }
        }
        auto cpP1 = [&](P1W w, int c) {
            #pragma unroll
            for (int r = 0; r < RPT; r++) {
                const float4 h = H1c[(rb + r) * SV4 + c];
                pkf(az[r][0], h.x, lo2(w.zA0)); pkf(az[r][0], h.y, hi2(w.zA0));
                pkf(az[r][0], h.z, lo2(w.zA1)); pkf(az[r][0], h.w, hi2(w.zA1));
                pkf(ar[r][0], h.x, lo2(w.rA0)); pkf(ar[r][0], h.y, hi2(w.rA0));
                pkf(ar[r][0], h.z, lo2(w.rA1)); pkf(ar[r][0], h.w, hi2(w.rA1));
                pkf(az[r][1], h.x, lo2(w.zB0)); pkf(az[r][1], h.y, hi2(w.zB0));
                pkf(az[r][1], h.z, lo2(w.zB1)); pkf(az[r][1], h.w, hi2(w.zB1));
                pkf(ar[r][1], h.x, lo2(w.rB0)); pkf(ar[r][1], h.y, hi2(w.rB0));
                pkf(ar[r][1], h.z, lo2(w.rB1)); pkf(ar[r][1], h.w, hi2(w.rB1));
            }
        };
        P1W a0 = ldP1(0), a1 = ldP1(1);
        for (int cb = 0; cb < 32; cb += 4) {
            P1W b0 = ldP1(cb + 2), b1 = ldP1(cb + 3);
            cpP1(a0, cb); cpP1(a1, cb + 1);
            if (cb + 4 < 32) { a0 = ldP1(cb + 4); a1 = ldP1(cb + 5); }
            cpP1(b0, cb + 2); cpP1(b1, cb + 3);
        }
        #pragma unroll
        for (int r = 0; r < RPT; r++) {
            const int row = rb + r;
            zg[r][0].x = sigmoidf(az[r][0].x);
            zg[r][0].y = sigmoidf(az[r][0].y);
            zg[r][1].x = sigmoidf(az[r][1].x);
            zg[r][1].y = sigmoidf(az[r][1].y);
            const float rA0 = sigmoidf(ar[r][0].x);
            const float rA1 = sigmoidf(ar[r][0].y);
            const float rB0 = sigmoidf(ar[r][1].x);
            const float rB1 = sigmoidf(ar[r][1].y);
            h1c[r][0].x = H1rd[row * S + f0A];
            h1c[r][0].y = H1rd[row * S + f0A + 64];
            h1c[r][1].x = H1rd[row * S + f0B];
            h1c[r][1].y = H1rd[row * S + f0B + 64];
            sHR1[row * S + f0A]      = h1c[r][0].x * rA0;
            sHR1[row * S + f0A + 64] = h1c[r][0].y * rA1;
            sHR1[row * S + f0B]      = h1c[r][1].x * rB0;
            sHR1[row * S + f0B + 64] = h1c[r][1].y * rB1;
        }
    };

    // P2 (A): layer-1 h gate + H1 update. Weight pipeline: 4-c groups.
    auto l1_p2 = [&](int s) {
        float* H1wr = sH1[s & 1];
        v2f ah[RPT][2];
        {
            const v2f wh1A = {sVec[256 + f0A], sVec[256 + f0A + 64]};
            const v2f wh1B = {sVec[256 + f0B], sVec[256 + f0B + 64]};
            const v2f ch1A = {sVec[640 + f0A], sVec[640 + f0A + 64]};
            const v2f ch1B = {sVec[640 + f0B], sVec[640 + f0B + 64]};
            #pragma unroll
            for (int r = 0; r < RPT; r++) {
                ah[r][0] = __builtin_elementwise_fma((v2f){axp[r], axp[r]}, wh1A, ch1A);
                ah[r][1] = __builtin_elementwise_fma((v2f){axp[r], axp[r]}, wh1B, ch1B);
            }
        }
        auto cpOne = [&](P2W w, int c) {
            #pragma unroll
            for (int r = 0; r < RPT; r++) {
                const float4 q = HR1v[(rb + r) * SV4 + c];
                pkf(ah[r][0], q.x, lo2(w.h0A)); pkf(ah[r][0], q.y, hi2(w.h0A));
                pkf(ah[r][0], q.z, lo2(w.h1A)); pkf(ah[r][0], q.w, hi2(w.h1A));
                pkf(ah[r][1], q.x, lo2(w.h0B)); pkf(ah[r][1], q.y, hi2(w.h0B));
                pkf(ah[r][1], q.z, lo2(w.h1B)); pkf(ah[r][1], q.w, hi2(w.h1B));
            }
        };
        auto cpG = [&](P2G g, int c0) {
            cpOne(g.c0, c0); cpOne(g.c1, c0 + 1);
            cpOne(g.c2, c0 + 2); cpOne(g.c3, c0 + 3);
        };
        P2G a = ldP2(Lh1, 0);
        for (int cb = 0; cb < 32; cb += 8) {
            P2G bgrp = ldP2(Lh1, cb + 4);
            cpG(a, cb);
            if (cb + 8 < 32) a = ldP2(Lh1, cb + 8);
            cpG(bgrp, cb + 4);
        }
        #pragma unroll
        for (int r = 0; r < RPT; r++) {
            const int row = rb + r;
            const float n0 = fmaf(zg[r][0].x, h1c[r][0].x, (1.0f - zg[r][0].x) * tanhf(ah[r][0].x));
            const float n1 = fmaf(zg[r][0].y, h1c[r][0].y, (1.0f - zg[r][0].y) * tanhf(ah[r][0].y));
            const float n2 = fmaf(zg[r][1].x, h1c[r][1].x, (1.0f - zg[r][1].x) * tanhf(ah[r][1].x));
            const float n3 = fmaf(zg[r][1].y, h1c[r][1].y, (1.0f - zg[r][1].y) * tanhf(ah[r][1].y));
            H1wr[row * S + f0A]      = n0;
            H1wr[row * S + f0A + 64] = n1;
            H1wr[row * S + f0B]      = n2;
            H1wr[row * S + f0B + 64] = n3;
        }
    };

    // P3 (B): AH = A @ H1(state tt) for own rows/cols (LDS only)
    auto l2_p3 = [&](int tt) {
        const float* H1rd = sH1[tt & 1];
        v2f aa[RPT][2];
        #pragma unroll
        for (int r = 0; r < RPT; r++) { aa[r][0] = (v2f){0.0f, 0.0f}; aa[r][1] = (v2f){0.0f, 0.0f}; }
        #pragma unroll 3
        for (int j = 0; j < NN; j++) {
            const v2f hjA = {H1rd[j * S + f0A], H1rd[j * S + f0A + 64]};
            const v2f hjB = {H1rd[j * S + f0B], H1rd[j * S + f0B + 64]};
            #pragma unroll
            for (int r = 0; r < RPT; r++) {
                const float arj = sA[(rb + r) * NN + j];
                aa[r][0] = __builtin_elementwise_fma((v2f){arj, arj}, hjA, aa[r][0]);
                aa[r][1] = __builtin_elementwise_fma((v2f){arj, arj}, hjB, aa[r][1]);
            }
        }
        #pragma unroll
        for (int r = 0; r < RPT; r++) {
            const int row = rb + r;
            sAH[row * S + f0A]      = aa[r][0].x;
            sAH[row * S + f0A + 64] = aa[r][0].y;
            sAH[row * S + f0B]      = aa[r][1].x;
            sAH[row * S + f0B + 64] = aa[r][1].y;
        }
    };

    // P4 (B): layer-2 gcn + z,r gates; h-gate a-chunk partials into ph.
    // Two per-pair passes; each pass: 1-c ping-pong (2 x P4W).
    // Chains stay c-ascending, a-chunk-then-q-chunk per gate -> bit-exact.
    auto l2_p4 = [&]() {
        v2f pz[RPT][2], pr[RPT][2];
        {
            const v2f cz2A = {sVec[768 + f0A],  sVec[768 + f0A + 64]};
            const v2f cz2B = {sVec[768 + f0B],  sVec[768 + f0B + 64]};
            const v2f cr2A = {sVec[896 + f0A],  sVec[896 + f0A + 64]};
            const v2f cr2B = {sVec[896 + f0B],  sVec[896 + f0B + 64]};
            const v2f ch2A = {sVec[1024 + f0A], sVec[1024 + f0A + 64]};
            const v2f ch2B = {sVec[1024 + f0B], sVec[1024 + f0B + 64]};
            #pragma unroll
            for (int r = 0; r < RPT; r++) {
                pz[r][0] = cz2A; pz[r][1] = cz2B;
                pr[r][0] = cr2A; pr[r][1] = cr2B;
                ph[r][0] = ch2A; ph[r][1] = ch2B;
            }
        }
        auto pass = [&](auto pc) {
            constexpr int P = decltype(pc)::v;
            const int f0 = P ? f0B : f0A;
            auto cp = [&](P4W w, int c) {
                #pragma unroll
                for (int r = 0; r < RPT; r++) {
                    const float4 a = AHv[(rb + r) * SV4 + c];
                    const float4 q = H2v[(rb + r) * SV4 + c];
                    pkf(pz[r][P], a.x, lo2(w.wz0)); pkf(pz[r][P], a.y, hi2(w.wz0));
                    pkf(pz[r][P], a.z, lo2(w.wz1)); pkf(pz[r][P], a.w, hi2(w.wz1));
                    pkf(pz[r][P], q.x, lo2(w.lz0)); pkf(pz[r][P], q.y, hi2(w.lz0));
                    pkf(pz[r][P], q.z, lo2(w.lz1)); pkf(pz[r][P], q.w, hi2(w.lz1));
                    pkf(pr[r][P], a.x, lo2(w.wr0)); pkf(pr[r][P], a.y, hi2(w.wr0));
                    pkf(pr[r][P], a.z, lo2(w.wr1)); pkf(pr[r][P], a.w, hi2(w.wr1));
                    pkf(pr[r][P], q.x, lo2(w.lr0)); pkf(pr[r][P], q.y, hi2(w.lr0));
                    pkf(pr[r][P], q.z, lo2(w.lr1)); pkf(pr[r][P], q.w, hi2(w.lr1));
                    pkf(ph[r][P], a.x, lo2(w.wh0)); pkf(ph[r][P], a.y, hi2(w.wh0));
                    pkf(ph[r][P], a.z, lo2(w.wh1)); pkf(ph[r][P], a.w, hi2(w.wh1));
                }
            };
            P4W wa = ldP4(0, f0);
            for (int c = 0; c < 32; c += 2) {
                P4W wb = ldP4(c + 1, f0);
                cp(wa, c);
                if (c + 2 < 32) wa = ldP4(c + 2, f0);
                cp(wb, c + 1);
            }
        };
        pass(ic<0>{});
        pass(ic<1>{});
        #pragma unroll
        for (int r = 0; r < RPT; r++) {
            const int row = rb + r;
            z2[r][0].x = sigmoidf(pz[r][0].x);
            z2[r][0].y = sigmoidf(pz[r][0].y);
            z2[r][1].x = sigmoidf(pz[r][1].x);
            z2[r][1].y = sigmoidf(pz[r][1].y);
            const float rA0 = sigmoidf(pr[r][0].x);
            const float rA1 = sigmoidf(pr[r][0].y);
            const float rB0 = sigmoidf(pr[r][1].x);
            const float rB1 = sigmoidf(pr[r][1].y);
            h2c[r][0].x = sH2[row * S + f0A];
            h2c[r][0].y = sH2[row * S + f0A + 64];
            h2c[r][1].x = sH2[row * S + f0B];
            h2c[r][1].y = sH2[row * S + f0B + 64];
            sHR2[row * S + f0A]      = h2c[r][0].x * rA0;
            sHR2[row * S + f0A + 64] = h2c[r][0].y * rA1;
            sHR2[row * S + f0B]      = h2c[r][1].x * rB0;
            sHR2[row * S + f0B + 64] = h2c[r][1].y * rB1;
        }
    };

    // P5 (B): layer-2 h gate finish + H2 update + output accum.
    // Weight pipeline: 4-c groups.
    auto l2_p5 = [&]() {
        auto cpOne = [&](P2W w, int c) {
            #pragma unroll
            for (int r = 0; r < RPT; r++) {
                const float4 q = HR2v[(rb + r) * SV4 + c];
                pkf(ph[r][0], q.x, lo2(w.h0A)); pkf(ph[r][0], q.y, hi2(w.h0A));
                pkf(ph[r][0], q.z, lo2(w.h1A)); pkf(ph[r][0], q.w, hi2(w.h1A));
                pkf(ph[r][1], q.x, lo2(w.h0B)); pkf(ph[r][1], q.y, hi2(w.h0B));
                pkf(ph[r][1], q.z, lo2(w.h1B)); pkf(ph[r][1], q.w, hi2(w.h1B));
            }
        };
        auto cpG = [&](P2G g, int c0) {
            cpOne(g.c0, c0); cpOne(g.c1, c0 + 1);
            cpOne(g.c2, c0 + 2); cpOne(g.c3, c0 + 3);
        };
        P2G a = ldP2(Lh2, 0);
        for (int cb = 0; cb < 32; cb += 8) {
            P2G bgrp = ldP2(Lh2, cb + 4);
            cpG(a, cb);
            if (cb + 8 < 32) a = ldP2(Lh2, cb + 8);
            cpG(bgrp, cb + 4);
        }
        #pragma unroll
        for (int r = 0; r < RPT; r++) {
            const int row = rb + r;
            const float mA0 = fmaf(z2[r][0].x, h2c[r][0].x, (1.0f - z2[r][0].x) * tanhf(ph[r][0].x));
            const float mA1 = fmaf(z2[r][0].y, h2c[r][0].y, (1.0f - z2[r][0].y) * tanhf(ph[r][0].y));
            const float mB0 = fmaf(z2[r][1].x, h2c[r][1].x, (1.0f - z2[r][1].x) * tanhf(ph[r][1].x));
            const float mB1 = fmaf(z2[r][1].y, h2c[r][1].y, (1.0f - z2[r][1].y) * tanhf(ph[r][1].y));
            sH2[row * S + f0A]      = mA0;
            sH2[row * S + f0A + 64] = mA1;
            sH2[row * S + f0B]      = mB0;
            sH2[row * S + f0B + 64] = mB1;
            if (row < NN) {
                oA0 += (double)mA0; oA1 += (double)mA1;
                oB0 += (double)mB0; oB1 += (double)mB1;
            }
        }
    };

    // ======== pipeline prologue: A computes step 0 ========
    if (isA) l1_p1(0);
    __syncthreads();
    if (isA) l1_p2(0);
    __syncthreads();

    // ======== main ticks: 2 barriers each ========
    for (int k = 0; k < TSTEPS; k++) {
        // alpha
        if (isA) {
            if (k + 1 < TSTEPS) l1_p1(k + 1);
        } else {
            if (k >= 1) l2_p5();     // finish step k-1
            l2_p3(k);
        }
        __syncthreads();  // b1: publishes sHR1(k+1), sAH(k), sH2(k-1)
        // beta
        if (isA) {
            if (k + 1 < TSTEPS) l1_p2(k + 1);
            if (t < NROW && k + 2 < TSTEPS) {   // sax prefetch for step k+2
                const float* xt = xb + (size_t)(k + 2) * NN;
                float a = 0.0f;
                for (int j = 0; j < NN; j++) a = fmaf(sA[t * NN + j], xt[j], a);
                sax[(k + 2) & 1][t] = a;
            }
        } else {
            l2_p4();
        }
        __syncthreads();  // b2: publishes H1(k+1), sHR2(k), sax(k+2)
    }

    // ---------- Epilogue: finish step T-1, mean over (T, nodes), cls ----------
    if (!isA) {
        l2_p5();  // step T-1 (sHR2 published at final b2)
        double vA0 = oA0, vA1 = oA1, vB0 = oB0, vB1 = oB1;
        #pragma unroll
        for (int off = 32; off >= 8; off >>= 1) {
            vA0 += __shfl_down(vA0, off, 64);
            vA1 += __shfl_down(vA1, off, 64);
            vB0 += __shfl_down(vB0, off, 64);
            vB1 += __shfl_down(vB1, off, 64);
        }
        if (rg == 0) {   // lane p of each B wave owns 4 columns
            sredD[f0A]      = vA0;
            sredD[f0A + 64] = vA1;
            sredD[f0B]      = vB0;
            sredD[f0B + 64] = vB1;
        }
    }
    __syncthreads();
    if (t < HID) {
        sredE[t] = (sredD[t] / (double)(TSTEPS * NN)) * (double)cls_w[t];
    }
    __syncthreads();
    if (t < 64) {
        double v = sredE[t] + sredE[t + 64];
        for (int off = 32; off; off >>= 1) v += __shfl_down(v, off, 64);
        if (t == 0) out[b] = (float)(v + (double)cls_b[0]);
    }
}

extern "C" void kernel_launch(void* const* d_in, const int* in_sizes, int n_in,
                              void* d_out, int out_size, void* d_ws, size_t ws_size,
                              hipStream_t stream) {
    const float* x    = (const float*)d_in[0];
    const int*   ei   = (const int*)  d_in[1];
    const float* ew   = (const float*)d_in[2];
    const float* Wz1  = (const float*)d_in[3];
    const float* bz1  = (const float*)d_in[4];
    const float* lzw1 = (const float*)d_in[5];
    const float* lzb1 = (const float*)d_in[6];
    const float* Wr1  = (const float*)d_in[7];
    const float* br1  = (const float*)d_in[8];
    const float* lrw1 = (const float*)d_in[9];
    const float* lrb1 = (const float*)d_in[10];
    const float* Wh1  = (const float*)d_in[11];
    const float* bh1  = (const float*)d_in[12];
    const float* lhw1 = (const float*)d_in[13];
    const float* lhb1 = (const float*)d_in[14];
    const float* Wz2  = (const float*)d_in[15];
    const float* bz2  = (const float*)d_in[16];
    const float* lzw2 = (const float*)d_in[17];
    const float* lzb2 = (const float*)d_in[18];
    const float* Wr2  = (const float*)d_in[19];
    const float* br2  = (const float*)d_in[20];
    const float* lrw2 = (const float*)d_in[21];
    const float* lrb2 = (const float*)d_in[22];
    const float* Wh2  = (const float*)d_in[23];
    const float* bh2  = (const float*)d_in[24];
    const float* lhw2 = (const float*)d_in[25];
    const float* lhb2 = (const float*)d_in[26];
    const float* clsw = (const float*)d_in[27];
    const float* clsb = (const float*)d_in[28];

    float* ws   = (float*)d_ws;
    float* outp = (float*)d_out;

    build_A<<<1, 64, 0, stream>>>(ei, ew, ws + WS_A);
    pack_bot<<<32, 256, 0, stream>>>(lzw1, lrw1, (float4*)(ws + WS_LZR1), 2);
    pack_bot<<<16, 256, 0, stream>>>(lhw1, lhw1, (float4*)(ws + WS_LH1), 1);
    pack_bot<<<32, 256, 0, stream>>>(lzw2, lrw2, (float4*)(ws + WS_LZR2), 2);
    pack_bot<<<16, 256, 0, stream>>>(lhw2, lhw2, (float4*)(ws + WS_LH2), 1);
    make_weff2<<<48, 256, 0, stream>>>(Wz2, Wr2, Wh2, lzw2, lrw2, lhw2,
                                       (float4*)(ws + WS_WE2));
    make_vecs<<<5, 256, 0, stream>>>(Wz1, Wr1, Wh1, bz1, br1, bh1,
                                     lzw1, lrw1, lhw1, lzb1, lrb1, lhb1,
                                     bz2, br2, bh2, lzw2, lrw2, lhw2,
                                     lzb2, lrb2, lhb2, ws + WS_VEC);
    tgcn_main<<<64, NTHREADS, 0, stream>>>(x, ws, clsw, clsb, outp);
}

// Round 7
// 18479.921 us; speedup vs baseline: 7.3190x; 2.2559x over previous
//
#include <hip/hip_runtime.h>
#include <hip/hip_bf16.h>

// TGCN: B=64, T=500, N=21, HID=128.
// Round 14 = Round 13 resubmitted (round-13 bench was an infra failure, no data).
// Round 13: give up on register ping-pong (two scratch disasters: r9-r12's
// conditional aggregate reassignment defeats SROA -> 2.2GB scratch writes,
// VGPR stuck 128, VALUBusy 8%). Revert to r8's PLAIN just-in-time loads
// (proven scratch-free) and attack the r8 bottleneck (latency at 2 waves/SIMD)
// with TLP: 1024 threads = 16 waves = 4 waves/SIMD. Each lane owns ONE
// column pair f0 = gw*8 + p (gw in 0..7), 3 rows. Per-element accumulation
// chains are bit-identical to r7/r8 (same c order, same intra-c sequence) ->
// absmax 0.0. NEVER reorder per-element sums in the recurrence.

#define NN 21
#define NROW 24            // padded rows (21,22,23 zero)
#define S 132              // padded float stride for H arrays (132%32==4)
#define SV4 33             // float4 stride
#define HID 128
#define TSTEPS 500
#define EDGES 210
#define NTHREADS 1024      // 16 waves: 8 per group
#define RPT 3              // rows per row-group

// ws layout (float offsets) — unchanged
#define WS_A     0
#define WS_VEC   1600
#define WS_LZR1  3200
#define WS_LH1   36000
#define WS_WE2   52400
#define WS_LZR2  101600
#define WS_LH2   134400

typedef float v2f __attribute__((ext_vector_type(2)));

__device__ __forceinline__ v2f lo2(float4 w) { v2f v = {w.x, w.y}; return v; }
__device__ __forceinline__ v2f hi2(float4 w) { v2f v = {w.z, w.w}; return v; }
__device__ __forceinline__ void pkf(v2f& acc, float s, v2f w) {
    v2f ss = {s, s};
    acc = __builtin_elementwise_fma(ss, w, acc);
}
__device__ __forceinline__ float sigmoidf(float v) {
    return 1.0f / (1.0f + expf(-v));
}

// ---- Prologue: build normalized adjacency A (21x21) in fp64, store fp32 ----
__global__ void build_A(const int* __restrict__ ei, const float* __restrict__ ew,
                        float* __restrict__ Aout) {
    __shared__ double deg[NN];
    __shared__ double dinv[NN];
    __shared__ double Asm[NN * NN];
    int t = threadIdx.x;
    for (int k = t; k < NN * NN; k += blockDim.x) Asm[k] = 0.0;
    if (t < NN) deg[t] = 1.0;  // self loop weight 1
    __syncthreads();
    if (t == 0) {
        for (int e = 0; e < EDGES; e++) deg[ei[EDGES + e]] += (double)ew[e];
        for (int i = 0; i < NN; i++) dinv[i] = deg[i] > 0.0 ? 1.0 / sqrt(deg[i]) : 0.0;
        for (int e = 0; e < EDGES; e++) {
            int s = ei[e], d = ei[EDGES + e];
            Asm[d * NN + s] += dinv[s] * (double)ew[e] * dinv[d];
        }
        for (int i = 0; i < NN; i++) Asm[i * NN + i] += dinv[i] * dinv[i];
    }
    __syncthreads();
    for (int k = t; k < NROW * NN; k += blockDim.x)
        Aout[k] = (k < NN * NN) ? (float)Asm[k] : 0.0f;
}

// ---- Prologue: repack bottom halves of (256,128) concat weights ----------
__global__ void pack_bot(const float* __restrict__ w0, const float* __restrict__ w1,
                         float4* __restrict__ out, int ngate) {
    int t = blockIdx.x * blockDim.x + threadIdx.x;
    int per_c = ngate * 128;
    int total = 32 * per_c;
    if (t >= total) return;
    int c = t / per_c, rem = t - c * per_c;
    int gate = rem >> 7;
    int r2 = rem & 127;
    int k2 = r2 >> 6;
    int f0 = r2 & 63;
    int k = 4 * c + 2 * k2;
    const float* src = (gate == 0) ? w0 : w1;
    float4 v;
    v.x = src[(128 + k) * 128 + f0];
    v.y = src[(128 + k) * 128 + f0 + 64];
    v.z = src[(128 + k + 1) * 128 + f0];
    v.w = src[(128 + k + 1) * 128 + f0 + 64];
    out[t] = v;
}

// ---- Prologue: Weff2_g = Wg_2 @ lgw_2_top, pair-interleaved, fp64 accum ----
__global__ void make_weff2(const float* __restrict__ Wz2, const float* __restrict__ Wr2,
                           const float* __restrict__ Wh2,
                           const float* __restrict__ lzw2, const float* __restrict__ lrw2,
                           const float* __restrict__ lhw2,
                           float4* __restrict__ out) {
    int t = blockIdx.x * blockDim.x + threadIdx.x;
    if (t >= 32 * 384) return;
    int c = t / 384, rem = t - c * 384;
    int g = rem >> 7;
    int r2 = rem & 127;
    int k2 = r2 >> 6;
    int f0 = r2 & 63;
    int k = 4 * c + 2 * k2;
    const float* W = (g == 0) ? Wz2 : (g == 1) ? Wr2 : Wh2;
    const float* L = (g == 0) ? lzw2 : (g == 1) ? lrw2 : lhw2;
    double a0 = 0, a1 = 0, a2 = 0, a3 = 0;
    for (int m = 0; m < 128; m++) {
        double w0 = (double)W[k * 128 + m];
        double w1 = (double)W[(k + 1) * 128 + m];
        a0 += w0 * (double)L[m * 128 + f0];
        a1 += w0 * (double)L[m * 128 + f0 + 64];
        a2 += w1 * (double)L[m * 128 + f0];
        a3 += w1 * (double)L[m * 128 + f0 + 64];
    }
    out[t] = make_float4((float)a0, (float)a1, (float)a2, (float)a3);
}

// ---- Prologue: layer-1 effective row vectors + all bias consts (fp64) ----
__global__ void make_vecs(const float* __restrict__ Wz1, const float* __restrict__ Wr1,
                          const float* __restrict__ Wh1,
                          const float* __restrict__ bz1, const float* __restrict__ br1,
                          const float* __restrict__ bh1,
                          const float* __restrict__ lzw1, const float* __restrict__ lrw1,
                          const float* __restrict__ lhw1,
                          const float* __restrict__ lzb1, const float* __restrict__ lrb1,
                          const float* __restrict__ lhb1,
                          const float* __restrict__ bz2, const float* __restrict__ br2,
                          const float* __restrict__ bh2,
                          const float* __restrict__ lzw2, const float* __restrict__ lrw2,
                          const float* __restrict__ lhw2,
                          const float* __restrict__ lzb2, const float* __restrict__ lrb2,
                          const float* __restrict__ lhb2,
                          float* __restrict__ out) {
    int t = blockIdx.x * blockDim.x + threadIdx.x;
    if (t >= 9 * 128) return;
    int v = t >> 7, f = t & 127;
    double acc = 0.0;
    if (v < 3) {
        const float* W = (v == 0) ? Wz1 : (v == 1) ? Wr1 : Wh1;
        const float* L = (v == 0) ? lzw1 : (v == 1) ? lrw1 : lhw1;
        for (int m = 0; m < 128; m++) acc += (double)W[m] * (double)L[m * 128 + f];
    } else if (v < 6) {
        int g = v - 3;
        const float* bb = (g == 0) ? bz1 : (g == 1) ? br1 : bh1;
        const float* L  = (g == 0) ? lzw1 : (g == 1) ? lrw1 : lhw1;
        const float* lb = (g == 0) ? lzb1 : (g == 1) ? lrb1 : lhb1;
        for (int m = 0; m < 128; m++) acc += (double)bb[m] * (double)L[m * 128 + f];
        acc += (double)lb[f];
    } else {
        int g = v - 6;
        const float* bb = (g == 0) ? bz2 : (g == 1) ? br2 : bh2;
        const float* L  = (g == 0) ? lzw2 : (g == 1) ? lrw2 : lhw2;
        const float* lb = (g == 0) ? lzb2 : (g == 1) ? lrb2 : lhb2;
        for (int m = 0; m < 128; m++) acc += (double)bb[m] * (double)L[m * 128 + f];
        acc += (double)lb[f];
    }
    out[t] = (float)acc;
}

// ---- Main: one block per batch, 16 waves (8 A + 8 B), 2 barriers/tick ----
__global__ __launch_bounds__(NTHREADS, 1) void tgcn_main(
    const float* __restrict__ x,       // (64,500,21)
    const float* __restrict__ ws,
    const float* __restrict__ cls_w,   // (128,1)
    const float* __restrict__ cls_b,   // (1,)
    float* __restrict__ out)           // (64,)
{
    const int b  = blockIdx.x;
    const int t  = threadIdx.x;
    const bool isA = (t < 512);                              // wave-uniform
    const int lt = t & 511;
    const int gw = __builtin_amdgcn_readfirstlane(lt >> 6);  // wave in group 0..7
    const int lane = t & 63;
    const int p  = lane & 7;          // pair slot
    const int rg = lane >> 3;         // row group 0..7
    const int rb = rg * RPT;          // first row of this lane
    const int f0 = gw * 8 + p;        // pair: cols (f0, f0+64)
    const int f1 = f0 + 64;

    __shared__ __align__(16) float sH1[2][NROW * S];  // double-buffered
    __shared__ __align__(16) float sH2[NROW * S];
    __shared__ __align__(16) float sHR1[NROW * S];
    __shared__ __align__(16) float sHR2[NROW * S];
    __shared__ __align__(16) float sAH[NROW * S];
    __shared__ float sA[NROW * NN];
    __shared__ float sVec[9 * 128];
    __shared__ float sax[2][NROW];
    __shared__ double sredD[HID];
    __shared__ double sredE[HID];

    const float4* Lzr1 = (const float4*)(ws + WS_LZR1);
    const float4* Lh1  = (const float4*)(ws + WS_LH1);
    const float4* We2  = (const float4*)(ws + WS_WE2);
    const float4* Lzr2 = (const float4*)(ws + WS_LZR2);
    const float4* Lh2  = (const float4*)(ws + WS_LH2);

    const float4* HR1v = (const float4*)sHR1;
    const float4* HR2v = (const float4*)sHR2;
    const float4* AHv  = (const float4*)sAH;
    const float4* H2v  = (const float4*)sH2;

    for (int k = t; k < 2 * NROW * S; k += NTHREADS) ((float*)sH1)[k] = 0.0f;
    for (int k = t; k < NROW * S; k += NTHREADS) {
        sH2[k] = 0.0f; sHR1[k] = 0.0f; sHR2[k] = 0.0f; sAH[k] = 0.0f;
    }
    for (int k = t; k < NROW * NN; k += NTHREADS) sA[k] = ws[WS_A + k];
    for (int k = t; k < 9 * 128; k += NTHREADS) sVec[k] = ws[WS_VEC + k];

    __syncthreads();

    const float* xb = x + (size_t)b * (TSTEPS * NN);
    if (t < NROW) {  // sax for steps 0 and 1 (slot = s&1)
        float a0s = 0.0f, a1s = 0.0f;
        for (int j = 0; j < NN; j++) {
            a0s = fmaf(sA[t * NN + j], xb[j], a0s);
            a1s = fmaf(sA[t * NN + j], xb[NN + j], a1s);
        }
        sax[0][t] = a0s;
        sax[1][t] = a1s;
    }
    __syncthreads();

    // ---- persistent per-thread state carried across barriers ----
    float axp[RPT];                   // A: P1 -> P2
    v2f zg[RPT], h1c[RPT];            // A: P1 -> P2
    v2f ph[RPT], z2[RPT], h2c[RPT];   // B: P4 -> P5 (crosses b2)
    double oacc0 = 0.0, oacc1 = 0.0;  // B output accum

    // ================= phase lambdas (plain just-in-time loads) ==============
    // P1 (A): layer-1 z,r gates for step s; reads H1 state s-1 = buf[(s+1)&1]
    auto l1_p1 = [&](int s) {
        const float* H1rd = sH1[(s + 1) & 1];
        const float4* H1c = (const float4*)H1rd;
        #pragma unroll
        for (int r = 0; r < RPT; r++) axp[r] = sax[s & 1][rb + r];
        v2f az[RPT], ar[RPT];
        {
            const v2f wz1v = {sVec[f0],       sVec[f1]};
            const v2f wr1v = {sVec[128 + f0], sVec[128 + f1]};
            const v2f cz1v = {sVec[384 + f0], sVec[384 + f1]};
            const v2f cr1v = {sVec[512 + f0], sVec[512 + f1]};
            #pragma unroll
            for (int r = 0; r < RPT; r++) {
                az[r] = __builtin_elementwise_fma((v2f){axp[r], axp[r]}, wz1v, cz1v);
                ar[r] = __builtin_elementwise_fma((v2f){axp[r], axp[r]}, wr1v, cr1v);
            }
        }
        #pragma unroll 2
        for (int c = 0; c < 32; ++c) {
            const float4 wz0 = Lzr1[c * 256 + f0];
            const float4 wz1 = Lzr1[c * 256 + 64 + f0];
            const float4 wr0 = Lzr1[c * 256 + 128 + f0];
            const float4 wr1 = Lzr1[c * 256 + 192 + f0];
            #pragma unroll
            for (int r = 0; r < RPT; r++) {
                const float4 h = H1c[(rb + r) * SV4 + c];
                pkf(az[r], h.x, lo2(wz0)); pkf(az[r], h.y, hi2(wz0));
                pkf(az[r], h.z, lo2(wz1)); pkf(az[r], h.w, hi2(wz1));
                pkf(ar[r], h.x, lo2(wr0)); pkf(ar[r], h.y, hi2(wr0));
                pkf(ar[r], h.z, lo2(wr1)); pkf(ar[r], h.w, hi2(wr1));
            }
        }
        #pragma unroll
        for (int r = 0; r < RPT; r++) {
            const int row = rb + r;
            zg[r].x = sigmoidf(az[r].x);
            zg[r].y = sigmoidf(az[r].y);
            const float r0 = sigmoidf(ar[r].x);
            const float r1 = sigmoidf(ar[r].y);
            h1c[r].x = H1rd[row * S + f0];
            h1c[r].y = H1rd[row * S + f1];
            sHR1[row * S + f0] = h1c[r].x * r0;
            sHR1[row * S + f1] = h1c[r].y * r1;
        }
    };

    // P2 (A): layer-1 h gate + H1 update for step s; writes buf[s&1]
    auto l1_p2 = [&](int s) {
        float* H1wr = sH1[s & 1];
        v2f ah[RPT];
        {
            const v2f wh1v = {sVec[256 + f0], sVec[256 + f1]};
            const v2f ch1v = {sVec[640 + f0], sVec[640 + f1]};
            #pragma unroll
            for (int r = 0; r < RPT; r++)
                ah[r] = __builtin_elementwise_fma((v2f){axp[r], axp[r]}, wh1v, ch1v);
        }
        #pragma unroll 4
        for (int c = 0; c < 32; ++c) {
            const float4 wh0 = Lh1[c * 128 + f0];
            const float4 wh1 = Lh1[c * 128 + 64 + f0];
            #pragma unroll
            for (int r = 0; r < RPT; r++) {
                const float4 q = HR1v[(rb + r) * SV4 + c];
                pkf(ah[r], q.x, lo2(wh0)); pkf(ah[r], q.y, hi2(wh0));
                pkf(ah[r], q.z, lo2(wh1)); pkf(ah[r], q.w, hi2(wh1));
            }
        }
        #pragma unroll
        for (int r = 0; r < RPT; r++) {
            const int row = rb + r;
            const float n0 = fmaf(zg[r].x, h1c[r].x, (1.0f - zg[r].x) * tanhf(ah[r].x));
            const float n1 = fmaf(zg[r].y, h1c[r].y, (1.0f - zg[r].y) * tanhf(ah[r].y));
            H1wr[row * S + f0] = n0;
            H1wr[row * S + f1] = n1;
        }
    };

    // P3 (B): AH = A @ H1(state tt) for own rows/cols (LDS only)
    auto l2_p3 = [&](int tt) {
        const float* H1rd = sH1[tt & 1];
        v2f aa[RPT];
        #pragma unroll
        for (int r = 0; r < RPT; r++) aa[r] = (v2f){0.0f, 0.0f};
        #pragma unroll 3
        for (int j = 0; j < NN; j++) {
            const v2f hj = {H1rd[j * S + f0], H1rd[j * S + f1]};
            #pragma unroll
            for (int r = 0; r < RPT; r++) {
                const float arj = sA[(rb + r) * NN + j];
                aa[r] = __builtin_elementwise_fma((v2f){arj, arj}, hj, aa[r]);
            }
        }
        #pragma unroll
        for (int r = 0; r < RPT; r++) {
            const int row = rb + r;
            sAH[row * S + f0] = aa[r].x;
            sAH[row * S + f1] = aa[r].y;
        }
    };

    // P4 (B): layer-2 gcn + z,r gates; h-gate a-chunk partials into ph.
    auto l2_p4 = [&]() {
        v2f pz[RPT], pr[RPT];
        {
            const v2f cz2v = {sVec[768 + f0],  sVec[768 + f1]};
            const v2f cr2v = {sVec[896 + f0],  sVec[896 + f1]};
            const v2f ch2v = {sVec[1024 + f0], sVec[1024 + f1]};
            #pragma unroll
            for (int r = 0; r < RPT; r++) { pz[r] = cz2v; pr[r] = cr2v; ph[r] = ch2v; }
        }
        #pragma unroll 2
        for (int c = 0; c < 32; ++c) {
            const float4 wz0 = We2[c * 384 + f0];
            const float4 wz1 = We2[c * 384 + 64 + f0];
            const float4 wr0 = We2[c * 384 + 128 + f0];
            const float4 wr1 = We2[c * 384 + 192 + f0];
            const float4 wh0 = We2[c * 384 + 256 + f0];
            const float4 wh1 = We2[c * 384 + 320 + f0];
            const float4 lz0 = Lzr2[c * 256 + f0];
            const float4 lz1 = Lzr2[c * 256 + 64 + f0];
            const float4 lr0 = Lzr2[c * 256 + 128 + f0];
            const float4 lr1 = Lzr2[c * 256 + 192 + f0];
            #pragma unroll
            for (int r = 0; r < RPT; r++) {
                const float4 a = AHv[(rb + r) * SV4 + c];
                const float4 q = H2v[(rb + r) * SV4 + c];
                // a-chunk then q-chunk per gate (round-7/8 order)
                pkf(pz[r], a.x, lo2(wz0)); pkf(pz[r], a.y, hi2(wz0));
                pkf(pz[r], a.z, lo2(wz1)); pkf(pz[r], a.w, hi2(wz1));
                pkf(pz[r], q.x, lo2(lz0)); pkf(pz[r], q.y, hi2(lz0));
                pkf(pz[r], q.z, lo2(lz1)); pkf(pz[r], q.w, hi2(lz1));
                pkf(pr[r], a.x, lo2(wr0)); pkf(pr[r], a.y, hi2(wr0));
                pkf(pr[r], a.z, lo2(wr1)); pkf(pr[r], a.w, hi2(wr1));
                pkf(pr[r], q.x, lo2(lr0)); pkf(pr[r], q.y, hi2(lr0));
                pkf(pr[r], q.z, lo2(lr1)); pkf(pr[r], q.w, hi2(lr1));
                pkf(ph[r], a.x, lo2(wh0)); pkf(ph[r], a.y, hi2(wh0));
                pkf(ph[r], a.z, lo2(wh1)); pkf(ph[r], a.w, hi2(wh1));
            }
        }
        #pragma unroll
        for (int r = 0; r < RPT; r++) {
            const int row = rb + r;
            z2[r].x = sigmoidf(pz[r].x);
            z2[r].y = sigmoidf(pz[r].y);
            const float r20 = sigmoidf(pr[r].x);
            const float r21 = sigmoidf(pr[r].y);
            h2c[r].x = sH2[row * S + f0];
            h2c[r].y = sH2[row * S + f1];
            sHR2[row * S + f0] = h2c[r].x * r20;
            sHR2[row * S + f1] = h2c[r].y * r21;
        }
    };

    // P5 (B): layer-2 h gate finish + H2 update + output accum.
    auto l2_p5 = [&]() {
        #pragma unroll 4
        for (int c = 0; c < 32; ++c) {
            const float4 lh0 = Lh2[c * 128 + f0];
            const float4 lh1 = Lh2[c * 128 + 64 + f0];
            #pragma unroll
            for (int r = 0; r < RPT; r++) {
                const float4 q = HR2v[(rb + r) * SV4 + c];
                pkf(ph[r], q.x, lo2(lh0)); pkf(ph[r], q.y, hi2(lh0));
                pkf(ph[r], q.z, lo2(lh1)); pkf(ph[r], q.w, hi2(lh1));
            }
        }
        #pragma unroll
        for (int r = 0; r < RPT; r++) {
            const int row = rb + r;
            const float m0 = fmaf(z2[r].x, h2c[r].x, (1.0f - z2[r].x) * tanhf(ph[r].x));
            const float m1 = fmaf(z2[r].y, h2c[r].y, (1.0f - z2[r].y) * tanhf(ph[r].y));
            sH2[row * S + f0] = m0;
            sH2[row * S + f1] = m1;
            if (row < NN) {
                oacc0 += (double)m0;
                oacc1 += (double)m1;
            }
        }
    };

    // ======== pipeline prologue: A computes step 0 ========
    if (isA) l1_p1(0);
    __syncthreads();
    if (isA) l1_p2(0);
    __syncthreads();

    // ======== main ticks: 2 barriers each ========
    for (int k = 0; k < TSTEPS; k++) {
        // alpha
        if (isA) {
            if (k + 1 < TSTEPS) l1_p1(k + 1);
        } else {
            if (k >= 1) l2_p5();     // finish step k-1
            l2_p3(k);
        }
        __syncthreads();  // b1: publishes sHR1(k+1), sAH(k), sH2(k-1)
        // beta
        if (isA) {
            if (k + 1 < TSTEPS) l1_p2(k + 1);
            if (t < NROW && k + 2 < TSTEPS) {   // sax prefetch for step k+2
                const float* xt = xb + (size_t)(k + 2) * NN;
                float a = 0.0f;
                for (int j = 0; j < NN; j++) a = fmaf(sA[t * NN + j], xt[j], a);
                sax[(k + 2) & 1][t] = a;
            }
        } else {
            l2_p4();
        }
        __syncthreads();  // b2: publishes H1(k+1), sHR2(k), sax(k+2)
    }

    // ---------- Epilogue: finish step T-1, mean over (T, nodes), cls ----------
    if (!isA) {
        l2_p5();  // step T-1 (sHR2 published at final b2)
        double v0 = oacc0, v1 = oacc1;
        #pragma unroll
        for (int off = 32; off >= 8; off >>= 1) {
            v0 += __shfl_down(v0, off, 64);
            v1 += __shfl_down(v1, off, 64);
        }
        if (rg == 0) {   // lane p of each B wave owns its pair's 2 columns
            sredD[f0] = v0;
            sredD[f1] = v1;
        }
    }
    __syncthreads();
    if (t < HID) {
        sredE[t] = (sredD[t] / (double)(TSTEPS * NN)) * (double)cls_w[t];
    }
    __syncthreads();
    if (t < 64) {
        double v = sredE[t] + sredE[t + 64];
        for (int off = 32; off; off >>= 1) v += __shfl_down(v, off, 64);
        if (t == 0) out[b] = (float)(v + (double)cls_b[0]);
    }
}

extern "C" void kernel_launch(void* const* d_in, const int* in_sizes, int n_in,
                              void* d_out, int out_size, void* d_ws, size_t ws_size,
                              hipStream_t stream) {
    const float* x    = (const float*)d_in[0];
    const int*   ei   = (const int*)  d_in[1];
    const float* ew   = (const float*)d_in[2];
    const float* Wz1  = (const float*)d_in[3];
    const float* bz1  = (const float*)d_in[4];
    const float* lzw1 = (const float*)d_in[5];
    const float* lzb1 = (const float*)d_in[6];
    const float* Wr1  = (const float*)d_in[7];
    const float* br1  = (const float*)d_in[8];
    const float* lrw1 = (const float*)d_in[9];
    const float* lrb1 = (const float*)d_in[10];
    const float* Wh1  = (const float*)d_in[11];
    const float* bh1  = (const float*)d_in[12];
    const float* lhw1 = (const float*)d_in[13];
    const float* lhb1 = (const float*)d_in[14];
    const float* Wz2  = (const float*)d_in[15];
    const float* bz2  = (const float*)d_in[16];
    const float* lzw2 = (const float*)d_in[17];
    const float* lzb2 = (const float*)d_in[18];
    const float* Wr2  = (const float*)d_in[19];
    const float* br2  = (const float*)d_in[20];
    const float* lrw2 = (const float*)d_in[21];
    const float* lrb2 = (const float*)d_in[22];
    const float* Wh2  = (const float*)d_in[23];
    const float* bh2  = (const float*)d_in[24];
    const float* lhw2 = (const float*)d_in[25];
    const float* lhb2 = (const float*)d_in[26];
    const float* clsw = (const float*)d_in[27];
    const float* clsb = (const float*)d_in[28];

    float* ws   = (float*)d_ws;
    float* outp = (float*)d_out;

    build_A<<<1, 64, 0, stream>>>(ei, ew, ws + WS_A);
    pack_bot<<<32, 256, 0, stream>>>(lzw1, lrw1, (float4*)(ws + WS_LZR1), 2);
    pack_bot<<<16, 256, 0, stream>>>(lhw1, lhw1, (float4*)(ws + WS_LH1), 1);
    pack_bot<<<32, 256, 0, stream>>>(lzw2, lrw2, (float4*)(ws + WS_LZR2), 2);
    pack_bot<<<16, 256, 0, stream>>>(lhw2, lhw2, (float4*)(ws + WS_LH2), 1);
    make_weff2<<<48, 256, 0, stream>>>(Wz2, Wr2, Wh2, lzw2, lrw2, lhw2,
                                       (float4*)(ws + WS_WE2));
    make_vecs<<<5, 256, 0, stream>>>(Wz1, Wr1, Wh1, bz1, br1, bh1,
                                     lzw1, lrw1, lhw1, lzb1, lrb1, lhb1,
                                     bz2, br2, bh2, lzw2, lrw2, lhw2,
                                     lzb2, lrb2, lhb2, ws + WS_VEC);
    tgcn_main<<<64, NTHREADS, 0, stream>>>(x, ws, clsw, clsb, outp);
}